// Round 1
// baseline (1409.459 us; speedup 1.0000x reference)
//
#include <hip/hip_runtime.h>
#include <hip/hip_bf16.h>
#include <math.h>

#define N_NODES 10000
#define N_EDGESI 120000
#define E_TOT   130000   /* with self loops */
#define F_INPUT 66
#define HEADS   10
#define F_HEAD  66
#define F_GAT   660      /* HEADS*F_HEAD */
#define F_GCN   1320
#define F_G1    1000
#define F_G2    64

__device__ __forceinline__ float lky(float x, float s){ return x >= 0.f ? x : s*x; }

/* ---------------- CSR build ---------------- */

__global__ void k_count(const int* __restrict__ ei, int* __restrict__ counts){
    int e = blockIdx.x*256 + threadIdx.x;
    if (e >= E_TOT) return;
    int dst = (e < N_EDGESI) ? ei[N_EDGESI + e] : (e - N_EDGESI);
    atomicAdd(&counts[dst], 1);
}

__global__ void k_scan(const int* __restrict__ counts, int* __restrict__ offsets){
    __shared__ int sh[256];
    int carry = 0;
    for (int base = 0; base < N_NODES; base += 256){
        int i = base + threadIdx.x;
        int v = (i < N_NODES) ? counts[i] : 0;
        sh[threadIdx.x] = v;
        __syncthreads();
        for (int off = 1; off < 256; off <<= 1){
            int t = (threadIdx.x >= off) ? sh[threadIdx.x - off] : 0;
            __syncthreads();
            sh[threadIdx.x] += t;
            __syncthreads();
        }
        if (i < N_NODES) offsets[i] = carry + sh[threadIdx.x] - v;
        int tot = sh[255];
        __syncthreads();
        carry += tot;
    }
    if (threadIdx.x == 0) offsets[N_NODES] = carry;
}

__global__ void k_fill(const int* __restrict__ ei, const int* __restrict__ offsets,
                       int* __restrict__ cursor,
                       int* __restrict__ src_sorted, int* __restrict__ dst_sorted){
    int e = blockIdx.x*256 + threadIdx.x;
    if (e >= E_TOT) return;
    int s, d;
    if (e < N_EDGESI){ s = ei[e]; d = ei[N_EDGESI + e]; }
    else { s = e - N_EDGESI; d = s; }
    int pos = offsets[d] + atomicAdd(&cursor[d], 1);
    src_sorted[pos] = s;
    dst_sorted[pos] = d;
}

/* ---------------- generic fp32 GEMM: C = act(A@B + bias) ----------------
   A[M,K] row-major, B[K,N] row-major. BM=BN=128, BK=16, 256 thr, 8x8 micro. */
__global__ __launch_bounds__(256)
void k_gemm(const float* __restrict__ A, const float* __restrict__ B,
            float* __restrict__ C, const float* __restrict__ bias,
            int M, int N, int K, float slope){
    __shared__ float As[16][128];
    __shared__ float Bs[16][128];
    int tid = threadIdx.x;
    int tx = tid & 15, ty = tid >> 4;
    int brow = blockIdx.y * 128, bcol = blockIdx.x * 128;

    float acc[8][8] = {};

    int a_kp = tid & 7;    /* k-pair 0..7 */
    int a_r0 = tid >> 3;   /* 0..31      */
    int b_c4 = tid & 31;   /* col4 0..31 */
    int b_kr = tid >> 5;   /* 0..7       */

    for (int k0 = 0; k0 < K; k0 += 16){
        #pragma unroll
        for (int p = 0; p < 4; p++){
            int r = a_r0 + p*32;
            int grow = brow + r;
            int gk = k0 + 2*a_kp;
            float2 v = make_float2(0.f, 0.f);
            if (grow < M && gk < K)   /* K always even -> pair guard ok */
                v = *(const float2*)(A + (size_t)grow*K + gk);
            As[2*a_kp  ][r] = v.x;
            As[2*a_kp+1][r] = v.y;
        }
        #pragma unroll
        for (int q = 0; q < 2; q++){
            int gk = k0 + b_kr + q*8;
            int gc = bcol + b_c4*4;
            float4 v = make_float4(0.f,0.f,0.f,0.f);
            if (gk < K){
                if (gc + 3 < N){
                    v = *(const float4*)(B + (size_t)gk*N + gc);
                } else {
                    if (gc     < N) v.x = B[(size_t)gk*N + gc];
                    if (gc + 1 < N) v.y = B[(size_t)gk*N + gc + 1];
                    if (gc + 2 < N) v.z = B[(size_t)gk*N + gc + 2];
                }
            }
            *(float4*)&Bs[b_kr + q*8][b_c4*4] = v;
        }
        __syncthreads();
        #pragma unroll
        for (int k = 0; k < 16; k++){
            float a[8], b[8];
            *(float4*)&a[0] = *(const float4*)&As[k][ty*8];
            *(float4*)&a[4] = *(const float4*)&As[k][ty*8+4];
            *(float4*)&b[0] = *(const float4*)&Bs[k][tx*8];
            *(float4*)&b[4] = *(const float4*)&Bs[k][tx*8+4];
            #pragma unroll
            for (int i = 0; i < 8; i++)
                #pragma unroll
                for (int j = 0; j < 8; j++)
                    acc[i][j] += a[i]*b[j];
        }
        __syncthreads();
    }

    #pragma unroll
    for (int i = 0; i < 8; i++){
        int r = brow + ty*8 + i;
        if (r < M){
            #pragma unroll
            for (int j = 0; j < 8; j++){
                int c = bcol + tx*8 + j;
                if (c < N){
                    float v = acc[i][j];
                    if (bias) v += bias[c];
                    C[(size_t)r*N + c] = (v >= 0.f) ? v : slope*v;
                }
            }
        }
    }
}

/* ---------------- GAT attention pieces ---------------- */

__global__ void k_attn_ad(const float* __restrict__ xt,
                          const float* __restrict__ att_src, const float* __restrict__ att_dst,
                          float* __restrict__ a_s, float* __restrict__ a_d){
    int t = blockIdx.x*256 + threadIdx.x;
    if (t >= N_NODES*HEADS) return;
    int n = t / HEADS, h = t % HEADS;
    const float* xr = xt + (size_t)n*F_GAT + h*F_HEAD;
    const float* as = att_src + h*F_HEAD;
    const float* ad = att_dst + h*F_HEAD;
    float s = 0.f, d = 0.f;
    for (int f = 0; f < F_HEAD; f++){ float v = xr[f]; s += v*as[f]; d += v*ad[f]; }
    a_s[t] = s; a_d[t] = d;
}

__global__ void k_edge(const int* __restrict__ src_sorted, const int* __restrict__ dst_sorted,
                       const float* __restrict__ a_s, const float* __restrict__ a_d,
                       float* __restrict__ e_sorted){
    int t = blockIdx.x*256 + threadIdx.x;
    if (t >= E_TOT*HEADS) return;
    int s = t / HEADS, h = t % HEADS;
    float v = a_s[src_sorted[s]*HEADS + h] + a_d[dst_sorted[s]*HEADS + h];
    e_sorted[t] = lky(v, 0.2f);
}

__global__ void k_softmax(const int* __restrict__ offsets,
                          float* __restrict__ e_sorted, float* __restrict__ inv_s){
    int t = blockIdx.x*256 + threadIdx.x;
    if (t >= N_NODES*HEADS) return;
    int n = t / HEADS, h = t % HEADS;
    int b = offsets[n], e = offsets[n+1];
    float m = -INFINITY;
    for (int s = b; s < e; s++) m = fmaxf(m, e_sorted[s*HEADS + h]);
    float sum = 0.f;
    for (int s = b; s < e; s++){
        float ex = __expf(e_sorted[s*HEADS + h] - m);
        e_sorted[s*HEADS + h] = ex;
        sum += ex;
    }
    inv_s[t] = 1.0f / fmaxf(sum, 1e-16f);
}

/* one block per node, 256 thr; 660 feats = 256+256+148 */
__global__ __launch_bounds__(256)
void k_gat_agg(const int* __restrict__ offsets, const int* __restrict__ src_sorted,
               const float* __restrict__ e_sorted, const float* __restrict__ inv_s,
               const float* __restrict__ xt, const float* __restrict__ b_gat,
               float* __restrict__ out){
    int n = blockIdx.x, tid = threadIdx.x;
    __shared__ float inv_sh[HEADS];
    if (tid < HEADS) inv_sh[tid] = inv_s[n*HEADS + tid];
    __syncthreads();
    int f0 = tid, f1 = tid + 256, f2 = tid + 512;
    int h0 = f0 / F_HEAD;
    int h1 = f1 / F_HEAD;
    int h2 = (f2 < F_GAT) ? (f2 / F_HEAD) : 0;
    float acc0 = 0.f, acc1 = 0.f, acc2 = 0.f;
    int b = offsets[n], e = offsets[n+1];
    for (int s = b; s < e; s++){
        int src = src_sorted[s];
        const float* xr = xt + (size_t)src*F_GAT;
        const float* er = e_sorted + (size_t)s*HEADS;
        acc0 += er[h0]*inv_sh[h0]*xr[f0];
        acc1 += er[h1]*inv_sh[h1]*xr[f1];
        if (f2 < F_GAT) acc2 += er[h2]*inv_sh[h2]*xr[f2];
    }
    float* orow = out + (size_t)n*F_GAT;
    orow[f0] = lky(acc0 + b_gat[f0], 0.01f);
    orow[f1] = lky(acc1 + b_gat[f1], 0.01f);
    if (f2 < F_GAT) orow[f2] = lky(acc2 + b_gat[f2], 0.01f);
}

/* ---------------- GCN ---------------- */

__global__ void k_dinv(const int* __restrict__ offsets, float* __restrict__ dinv){
    int n = blockIdx.x*256 + threadIdx.x;
    if (n >= N_NODES) return;
    float deg = (float)(offsets[n+1] - offsets[n]);
    dinv[n] = rsqrtf(fmaxf(deg, 1.0f));
}

/* one block per node; 1320 feats = 5*256 + 40 */
__global__ __launch_bounds__(256)
void k_gcn_agg(const int* __restrict__ offsets, const int* __restrict__ src_sorted,
               const float* __restrict__ dinv, const float* __restrict__ xt2,
               const float* __restrict__ b_gcn, float* __restrict__ out){
    int n = blockIdx.x, tid = threadIdx.x;
    float acc[6] = {0.f,0.f,0.f,0.f,0.f,0.f};
    int b = offsets[n], e = offsets[n+1];
    float di_n = dinv[n];
    for (int s = b; s < e; s++){
        int src = src_sorted[s];
        float norm = di_n * dinv[src];
        const float* xr = xt2 + (size_t)src*F_GCN;
        #pragma unroll
        for (int j = 0; j < 6; j++){
            int f = tid + j*256;
            if (f < F_GCN) acc[j] += norm * xr[f];
        }
    }
    float* orow = out + (size_t)n*F_GCN;
    #pragma unroll
    for (int j = 0; j < 6; j++){
        int f = tid + j*256;
        if (f < F_GCN) orow[f] = lky(acc[j] + b_gcn[f], 0.01f);
    }
}

/* ---------------- fused tail MLP: 64->32->16->1 ---------------- */
__global__ __launch_bounds__(256)
void k_tail(const float* __restrict__ h4,
            const float* __restrict__ Wfc1, const float* __restrict__ bfc1,
            const float* __restrict__ Wfc2, const float* __restrict__ bfc2,
            const float* __restrict__ Wout, const float* __restrict__ bout,
            float* __restrict__ out){
    __shared__ float W1[64*32];
    __shared__ float W2[32*16];
    __shared__ float Wo[16];
    __shared__ float b1[32];
    __shared__ float b2[16];
    __shared__ float r1[8][32];
    __shared__ float r2[8][16];
    int tid = threadIdx.x;
    for (int i = tid; i < 64*32; i += 256) W1[i] = Wfc1[i];
    for (int i = tid; i < 32*16; i += 256) W2[i] = Wfc2[i];
    if (tid < 16) Wo[tid] = Wout[tid];
    if (tid < 32) b1[tid] = bfc1[tid];
    if (tid < 16) b2[tid] = bfc2[tid];
    __syncthreads();
    int g = tid >> 5, j = tid & 31;
    int node = blockIdx.x*8 + g;
    const float* hr = h4 + (size_t)node*F_G2;
    float acc = 0.f;
    #pragma unroll 8
    for (int i = 0; i < 64; i++) acc += hr[i]*W1[i*32 + j];
    r1[g][j] = lky(acc + b1[j], 0.01f);
    __syncthreads();
    if (j < 16){
        float a2 = 0.f;
        #pragma unroll
        for (int i = 0; i < 32; i++) a2 += r1[g][i]*W2[i*16 + j];
        r2[g][j] = lky(a2 + b2[j], 0.01f);
    }
    __syncthreads();
    if (j == 0){
        float a3 = 0.f;
        #pragma unroll
        for (int i = 0; i < 16; i++) a3 += r2[g][i]*Wo[i];
        out[node] = a3 + bout[0];
    }
}

/* ---------------- launch ---------------- */

extern "C" void kernel_launch(void* const* d_in, const int* in_sizes, int n_in,
                              void* d_out, int out_size, void* d_ws, size_t ws_size,
                              hipStream_t stream){
    const float* x       = (const float*)d_in[0];
    const int*   ei      = (const int*)  d_in[1];
    const float* W_gat   = (const float*)d_in[2];
    const float* att_src = (const float*)d_in[3];
    const float* att_dst = (const float*)d_in[4];
    const float* b_gat   = (const float*)d_in[5];
    const float* W_gcn   = (const float*)d_in[6];
    const float* b_gcn   = (const float*)d_in[7];
    const float* W_g1    = (const float*)d_in[8];
    const float* b_g1    = (const float*)d_in[9];
    const float* W_g2    = (const float*)d_in[10];
    const float* b_g2    = (const float*)d_in[11];
    const float* W_fc1   = (const float*)d_in[12];
    const float* b_fc1   = (const float*)d_in[13];
    const float* W_fc2   = (const float*)d_in[14];
    const float* b_fc2   = (const float*)d_in[15];
    const float* W_out   = (const float*)d_in[16];
    const float* b_out   = (const float*)d_in[17];
    float* out = (float*)d_out;
    char* ws = (char*)d_ws;

    /* arena layout (aligned to 256B) */
    size_t off = 0;
    auto alloc = [&](size_t bytes){ size_t o = off; off += (bytes + 255) & ~(size_t)255; return o; };
    size_t o_counts = alloc(N_NODES*4);
    size_t o_cursor = alloc(N_NODES*4);
    size_t o_offs   = alloc((N_NODES+1)*4);
    size_t o_as     = alloc(N_NODES*HEADS*4);
    size_t o_ad     = alloc(N_NODES*HEADS*4);
    size_t o_invs   = alloc(N_NODES*HEADS*4);
    size_t o_dinv   = alloc(N_NODES*4);
    size_t o_srcs   = alloc(E_TOT*4);
    size_t o_dsts   = alloc(E_TOT*4);
    size_t o_esrt   = alloc((size_t)E_TOT*HEADS*4);
    size_t o_h1     = alloc((size_t)N_NODES*F_GAT*4);
    size_t o_R      = alloc((size_t)N_NODES*F_GCN*4*2);  /* 105.6 MB region */

    int*   counts   = (int*)(ws + o_counts);
    int*   cursor   = (int*)(ws + o_cursor);
    int*   offsets  = (int*)(ws + o_offs);
    float* a_s      = (float*)(ws + o_as);
    float* a_d      = (float*)(ws + o_ad);
    float* inv_s    = (float*)(ws + o_invs);
    float* dinv     = (float*)(ws + o_dinv);
    int*   src_srt  = (int*)(ws + o_srcs);
    int*   dst_srt  = (int*)(ws + o_dsts);
    float* e_srt    = (float*)(ws + o_esrt);
    float* h1b      = (float*)(ws + o_h1);
    float* R        = (float*)(ws + o_R);
    /* region overlays (phase-disjoint lifetimes) */
    float* xt  = R;                              /* phase A: 10000*660  */
    float* xt2 = R;                              /* phase B: 10000*1320 (xt dead) */
    float* h2b = R + (size_t)N_NODES*F_GCN;      /* phase B/C           */
    float* h3b = R;                              /* phase C: 10000*1000 (xt2 dead)*/
    float* h4b = R + (size_t)N_NODES*F_G1;       /* phase C: 10000*64   */

    /* CSR build */
    hipMemsetAsync(counts, 0, N_NODES*4, stream);
    hipMemsetAsync(cursor, 0, N_NODES*4, stream);
    k_count<<<(E_TOT+255)/256, 256, 0, stream>>>(ei, counts);
    k_scan<<<1, 256, 0, stream>>>(counts, offsets);
    k_fill<<<(E_TOT+255)/256, 256, 0, stream>>>(ei, offsets, cursor, src_srt, dst_srt);

    /* GAT */
    k_gemm<<<dim3((F_GAT+127)/128, (N_NODES+127)/128), 256, 0, stream>>>(
        x, W_gat, xt, nullptr, N_NODES, F_GAT, F_INPUT, 1.0f);
    k_attn_ad<<<(N_NODES*HEADS+255)/256, 256, 0, stream>>>(xt, att_src, att_dst, a_s, a_d);
    k_edge<<<((size_t)E_TOT*HEADS+255)/256, 256, 0, stream>>>(src_srt, dst_srt, a_s, a_d, e_srt);
    k_softmax<<<(N_NODES*HEADS+255)/256, 256, 0, stream>>>(offsets, e_srt, inv_s);
    k_gat_agg<<<N_NODES, 256, 0, stream>>>(offsets, src_srt, e_srt, inv_s, xt, b_gat, h1b);

    /* GCN */
    k_gemm<<<dim3((F_GCN+127)/128, (N_NODES+127)/128), 256, 0, stream>>>(
        h1b, W_gcn, xt2, nullptr, N_NODES, F_GCN, F_GAT, 1.0f);
    k_dinv<<<(N_NODES+255)/256, 256, 0, stream>>>(offsets, dinv);
    k_gcn_agg<<<N_NODES, 256, 0, stream>>>(offsets, src_srt, dinv, xt2, b_gcn, h2b);

    /* dense tail */
    k_gemm<<<dim3((F_G1+127)/128, (N_NODES+127)/128), 256, 0, stream>>>(
        h2b, W_g1, h3b, b_g1, N_NODES, F_G1, F_GCN, 0.01f);
    k_gemm<<<dim3((F_G2+127)/128, (N_NODES+127)/128), 256, 0, stream>>>(
        h3b, W_g2, h4b, b_g2, N_NODES, F_G2, F_G1, 0.01f);
    k_tail<<<N_NODES/8, 256, 0, stream>>>(h4b, W_fc1, b_fc1, W_fc2, b_fc2,
                                          W_out, b_out, out);
}

// Round 2
// 497.908 us; speedup vs baseline: 2.8308x; 2.8308x over previous
//
#include <hip/hip_runtime.h>
#include <hip/hip_bf16.h>
#include <math.h>

#define N_NODES 10000
#define MPAD    10112    /* 79*128 */
#define N_EDGESI 120000
#define E_TOT   130000   /* with self loops */
#define F_INPUT 66
#define HEADS   10
#define F_HEAD  66
#define F_GAT   660      /* HEADS*F_HEAD */
#define F_GCN   1320
#define F_G1    1000
#define F_G2    64

typedef _Float16 half_t;
typedef __attribute__((ext_vector_type(8))) _Float16 f16x8;
typedef __attribute__((ext_vector_type(4))) float f32x4;

/* padded K / N for fp16 MFMA GEMMs (K mult of 64, N mult of 128) */
#define KP_GAT 128
#define NP_GAT 768
#define KP_GCN 704
#define NP_GCN 1408
#define KP_G1  1344
#define NP_G1  1024
#define KP_G2  1024
#define NP_G2  128

__device__ __forceinline__ float lky(float x, float s){ return x >= 0.f ? x : s*x; }

#if defined(__has_builtin)
#if __has_builtin(__builtin_amdgcn_global_load_lds)
#define HAVE_GLL 1
#endif
#endif

#ifdef HAVE_GLL
#define LDSLOAD16(g, l) __builtin_amdgcn_global_load_lds( \
    (const __attribute__((address_space(1))) void*)(g),   \
    (__attribute__((address_space(3))) void*)(l), 16, 0, 0)
#else
#define LDSLOAD16(g, l) (*(f16x8*)(l) = *(const f16x8*)(g))
#endif

/* ---------------- CSR build ---------------- */

__global__ void k_count(const int* __restrict__ ei, int* __restrict__ counts){
    int e = blockIdx.x*256 + threadIdx.x;
    if (e >= E_TOT) return;
    int dst = (e < N_EDGESI) ? ei[N_EDGESI + e] : (e - N_EDGESI);
    atomicAdd(&counts[dst], 1);
}

__global__ void k_scan(const int* __restrict__ counts, int* __restrict__ offsets){
    __shared__ int sh[256];
    int carry = 0;
    for (int base = 0; base < N_NODES; base += 256){
        int i = base + threadIdx.x;
        int v = (i < N_NODES) ? counts[i] : 0;
        sh[threadIdx.x] = v;
        __syncthreads();
        for (int off = 1; off < 256; off <<= 1){
            int t = (threadIdx.x >= off) ? sh[threadIdx.x - off] : 0;
            __syncthreads();
            sh[threadIdx.x] += t;
            __syncthreads();
        }
        if (i < N_NODES) offsets[i] = carry + sh[threadIdx.x] - v;
        int tot = sh[255];
        __syncthreads();
        carry += tot;
    }
    if (threadIdx.x == 0) offsets[N_NODES] = carry;
}

__global__ void k_fill(const int* __restrict__ ei, const int* __restrict__ offsets,
                       int* __restrict__ cursor,
                       int* __restrict__ src_sorted, int* __restrict__ dst_sorted){
    int e = blockIdx.x*256 + threadIdx.x;
    if (e >= E_TOT) return;
    int s, d;
    if (e < N_EDGESI){ s = ei[e]; d = ei[N_EDGESI + e]; }
    else { s = e - N_EDGESI; d = s; }
    int pos = offsets[d] + atomicAdd(&cursor[d], 1);
    src_sorted[pos] = s;
    dst_sorted[pos] = d;
}

/* ---------------- fp32 -> fp16 packers ---------------- */

/* x [10000][66] -> xh [MPAD][128], zero-padded */
__global__ void k_xh(const float* __restrict__ x, half_t* __restrict__ xh){
    int idx = blockIdx.x*256 + threadIdx.x;
    if (idx >= MPAD*KP_GAT) return;
    int r = idx >> 7, c = idx & 127;
    float v = (r < N_NODES && c < F_INPUT) ? x[r*F_INPUT + c] : 0.f;
    xh[idx] = (half_t)v;
}

/* W [K][N] f32 -> WT [Np][Kp] f16, zero-padded everywhere outside */
__global__ void k_wt(const float* __restrict__ W, half_t* __restrict__ WT,
                     int K, int N, int Kp, int Np){
    int idx = blockIdx.x*256 + threadIdx.x;
    if (idx >= Np*Kp) return;
    int n = idx / Kp, k = idx - n*Kp;
    float v = (n < N && k < K) ? W[(size_t)k*N + n] : 0.f;
    WT[idx] = (half_t)v;
}

/* ---------------- fp16 MFMA GEMM ----------------
   C[M][ldc](f16) = act(A[MPAD][Kp](f16) @ Bt[Np][Kp]^T(f16) + bias)
   128x128 tile, BK=64, 4 waves (2x2), 4x4 16x16 frags per wave.
   LDS XOR swizzle: chunk' = chunk ^ (row&7) (both-sides involution). */
__global__ __launch_bounds__(256)
void k_hgemm(const half_t* __restrict__ A, const half_t* __restrict__ Bt,
             half_t* __restrict__ C, const float* __restrict__ bias,
             int Nreal, int ldc, int Kp, float slope){
    __shared__ half_t As[128*64];
    __shared__ half_t Bs[128*64];
    const int tid = threadIdx.x;
    const int l = tid & 63;
    const int wid = tid >> 6;
    const int wr = wid >> 1, wc = wid & 1;
    const int brow = blockIdx.y * 128;
    const int bcol = blockIdx.x * 128;

    f32x4 acc[4][4] = {};

    for (int k0 = 0; k0 < Kp; k0 += 64){
        #pragma unroll
        for (int i = 0; i < 4; i++){
            int s = tid + i*256;          /* 16B slot index, 0..1023 */
            int row = s >> 3, chp = s & 7;
            int ch = chp ^ (row & 7);     /* inverse-swizzled source chunk */
            LDSLOAD16(A  + (size_t)(brow+row)*Kp + k0 + ch*8, &As[s*8]);
            LDSLOAD16(Bt + (size_t)(bcol+row)*Kp + k0 + ch*8, &Bs[s*8]);
        }
        __syncthreads();
        #pragma unroll
        for (int t = 0; t < 2; t++){
            f16x8 af[4], bf[4];
            #pragma unroll
            for (int m = 0; m < 4; m++){
                int row = wr*64 + m*16 + (l & 15);
                int ch = (t*4 + (l >> 4)) ^ (row & 7);
                af[m] = *(const f16x8*)&As[row*64 + ch*8];
            }
            #pragma unroll
            for (int n = 0; n < 4; n++){
                int row = wc*64 + n*16 + (l & 15);
                int ch = (t*4 + (l >> 4)) ^ (row & 7);
                bf[n] = *(const f16x8*)&Bs[row*64 + ch*8];
            }
            #pragma unroll
            for (int m = 0; m < 4; m++)
                #pragma unroll
                for (int n = 0; n < 4; n++)
                    acc[m][n] = __builtin_amdgcn_mfma_f32_16x16x32_f16(
                        af[m], bf[n], acc[m][n], 0, 0, 0);
        }
        __syncthreads();
    }

    /* epilogue: bias + leaky + f16 store; write cols < ldc, zero for col>=Nreal */
    #pragma unroll
    for (int m = 0; m < 4; m++){
        #pragma unroll
        for (int n = 0; n < 4; n++){
            int col = bcol + wc*64 + n*16 + (l & 15);
            if (col >= ldc) continue;
            float bv = (bias && col < Nreal) ? bias[col] : 0.f;
            #pragma unroll
            for (int r = 0; r < 4; r++){
                int rowg = brow + wr*64 + m*16 + ((l >> 4) << 2) + r;
                float v = (col < Nreal) ? acc[m][n][r] + bv : 0.f;
                v = (v >= 0.f) ? v : slope*v;
                C[(size_t)rowg*ldc + col] = (half_t)v;
            }
        }
    }
}

/* ---------------- GAT attention pieces ---------------- */

__global__ void k_attn_ad(const half_t* __restrict__ xt,
                          const float* __restrict__ att_src, const float* __restrict__ att_dst,
                          float* __restrict__ a_s, float* __restrict__ a_d){
    int t = blockIdx.x*256 + threadIdx.x;
    if (t >= N_NODES*HEADS) return;
    int n = t / HEADS, h = t % HEADS;
    const half_t* xr = xt + (size_t)n*NP_GAT + h*F_HEAD;
    const float* as = att_src + h*F_HEAD;
    const float* ad = att_dst + h*F_HEAD;
    float s = 0.f, d = 0.f;
    for (int f = 0; f < F_HEAD; f++){ float v = (float)xr[f]; s += v*as[f]; d += v*ad[f]; }
    a_s[t] = s; a_d[t] = d;
}

__global__ void k_edge(const int* __restrict__ src_sorted, const int* __restrict__ dst_sorted,
                       const float* __restrict__ a_s, const float* __restrict__ a_d,
                       float* __restrict__ e_sorted){
    int t = blockIdx.x*256 + threadIdx.x;
    if (t >= E_TOT*HEADS) return;
    int s = t / HEADS, h = t % HEADS;
    float v = a_s[src_sorted[s]*HEADS + h] + a_d[dst_sorted[s]*HEADS + h];
    e_sorted[t] = lky(v, 0.2f);
}

__global__ void k_softmax(const int* __restrict__ offsets,
                          float* __restrict__ e_sorted, float* __restrict__ inv_s){
    int t = blockIdx.x*256 + threadIdx.x;
    if (t >= N_NODES*HEADS) return;
    int n = t / HEADS, h = t % HEADS;
    int b = offsets[n], e = offsets[n+1];
    float m = -INFINITY;
    for (int s = b; s < e; s++) m = fmaxf(m, e_sorted[s*HEADS + h]);
    float sum = 0.f;
    for (int s = b; s < e; s++){
        float ex = __expf(e_sorted[s*HEADS + h] - m);
        e_sorted[s*HEADS + h] = ex;
        sum += ex;
    }
    inv_s[t] = 1.0f / fmaxf(sum, 1e-16f);
}

/* one block per node, 256 thr; 660 feats = 256+256+148; writes f16 h1h [MPAD][704] */
__global__ __launch_bounds__(256)
void k_gat_agg(const int* __restrict__ offsets, const int* __restrict__ src_sorted,
               const float* __restrict__ e_sorted, const float* __restrict__ inv_s,
               const half_t* __restrict__ xt, const float* __restrict__ b_gat,
               half_t* __restrict__ out){
    int n = blockIdx.x, tid = threadIdx.x;
    __shared__ float inv_sh[HEADS];
    if (tid < HEADS) inv_sh[tid] = inv_s[n*HEADS + tid];
    __syncthreads();
    int f0 = tid, f1 = tid + 256, f2 = tid + 512;
    int h0 = f0 / F_HEAD;
    int h1 = f1 / F_HEAD;
    int h2 = (f2 < F_GAT) ? (f2 / F_HEAD) : 0;
    float acc0 = 0.f, acc1 = 0.f, acc2 = 0.f;
    int b = offsets[n], e = offsets[n+1];
    for (int s = b; s < e; s++){
        int src = src_sorted[s];
        const half_t* xr = xt + (size_t)src*NP_GAT;
        const float* er = e_sorted + (size_t)s*HEADS;
        acc0 += er[h0]*inv_sh[h0]*(float)xr[f0];
        acc1 += er[h1]*inv_sh[h1]*(float)xr[f1];
        if (f2 < F_GAT) acc2 += er[h2]*inv_sh[h2]*(float)xr[f2];
    }
    half_t* orow = out + (size_t)n*KP_GCN;
    orow[f0] = (half_t)lky(acc0 + b_gat[f0], 0.01f);
    orow[f1] = (half_t)lky(acc1 + b_gat[f1], 0.01f);
    if (f2 < F_GAT) orow[f2] = (half_t)lky(acc2 + b_gat[f2], 0.01f);
}

/* ---------------- GCN ---------------- */

__global__ void k_dinv(const int* __restrict__ offsets, float* __restrict__ dinv){
    int n = blockIdx.x*256 + threadIdx.x;
    if (n >= N_NODES) return;
    float deg = (float)(offsets[n+1] - offsets[n]);
    dinv[n] = rsqrtf(fmaxf(deg, 1.0f));
}

/* one block per node; 1320 feats; reads xt2 f16 [MPAD][1344], writes h2h f16 [MPAD][1344] */
__global__ __launch_bounds__(256)
void k_gcn_agg(const int* __restrict__ offsets, const int* __restrict__ src_sorted,
               const float* __restrict__ dinv, const half_t* __restrict__ xt2,
               const float* __restrict__ b_gcn, half_t* __restrict__ out){
    int n = blockIdx.x, tid = threadIdx.x;
    float acc[6] = {0.f,0.f,0.f,0.f,0.f,0.f};
    int b = offsets[n], e = offsets[n+1];
    float di_n = dinv[n];
    for (int s = b; s < e; s++){
        int src = src_sorted[s];
        float norm = di_n * dinv[src];
        const half_t* xr = xt2 + (size_t)src*KP_G1;
        #pragma unroll
        for (int j = 0; j < 6; j++){
            int f = tid + j*256;
            if (f < F_GCN) acc[j] += norm * (float)xr[f];
        }
    }
    half_t* orow = out + (size_t)n*KP_G1;
    #pragma unroll
    for (int j = 0; j < 6; j++){
        int f = tid + j*256;
        if (f < F_GCN) orow[f] = (half_t)lky(acc[j] + b_gcn[f], 0.01f);
    }
}

/* ---------------- fused tail MLP: 64->32->16->1 ---------------- */
__global__ __launch_bounds__(256)
void k_tail(const half_t* __restrict__ h4,
            const float* __restrict__ Wfc1, const float* __restrict__ bfc1,
            const float* __restrict__ Wfc2, const float* __restrict__ bfc2,
            const float* __restrict__ Wout, const float* __restrict__ bout,
            float* __restrict__ out){
    __shared__ float W1[64*32];
    __shared__ float W2[32*16];
    __shared__ float Wo[16];
    __shared__ float b1[32];
    __shared__ float b2[16];
    __shared__ float r1[8][32];
    __shared__ float r2[8][16];
    int tid = threadIdx.x;
    for (int i = tid; i < 64*32; i += 256) W1[i] = Wfc1[i];
    for (int i = tid; i < 32*16; i += 256) W2[i] = Wfc2[i];
    if (tid < 16) Wo[tid] = Wout[tid];
    if (tid < 32) b1[tid] = bfc1[tid];
    if (tid < 16) b2[tid] = bfc2[tid];
    __syncthreads();
    int g = tid >> 5, j = tid & 31;
    int node = blockIdx.x*8 + g;
    const half_t* hr = h4 + (size_t)node*F_G2;
    float acc = 0.f;
    #pragma unroll 8
    for (int i = 0; i < 64; i++) acc += (float)hr[i]*W1[i*32 + j];
    r1[g][j] = lky(acc + b1[j], 0.01f);
    __syncthreads();
    if (j < 16){
        float a2 = 0.f;
        #pragma unroll
        for (int i = 0; i < 32; i++) a2 += r1[g][i]*W2[i*16 + j];
        r2[g][j] = lky(a2 + b2[j], 0.01f);
    }
    __syncthreads();
    if (j == 0){
        float a3 = 0.f;
        #pragma unroll
        for (int i = 0; i < 16; i++) a3 += r2[g][i]*Wo[i];
        out[node] = a3 + bout[0];
    }
}

/* ---------------- launch ---------------- */

extern "C" void kernel_launch(void* const* d_in, const int* in_sizes, int n_in,
                              void* d_out, int out_size, void* d_ws, size_t ws_size,
                              hipStream_t stream){
    const float* x       = (const float*)d_in[0];
    const int*   ei      = (const int*)  d_in[1];
    const float* W_gat   = (const float*)d_in[2];
    const float* att_src = (const float*)d_in[3];
    const float* att_dst = (const float*)d_in[4];
    const float* b_gat   = (const float*)d_in[5];
    const float* W_gcn   = (const float*)d_in[6];
    const float* b_gcn   = (const float*)d_in[7];
    const float* W_g1    = (const float*)d_in[8];
    const float* b_g1    = (const float*)d_in[9];
    const float* W_g2    = (const float*)d_in[10];
    const float* b_g2    = (const float*)d_in[11];
    const float* W_fc1   = (const float*)d_in[12];
    const float* b_fc1   = (const float*)d_in[13];
    const float* W_fc2   = (const float*)d_in[14];
    const float* b_fc2   = (const float*)d_in[15];
    const float* W_out   = (const float*)d_in[16];
    const float* b_out   = (const float*)d_in[17];
    float* out = (float*)d_out;
    char* ws = (char*)d_ws;

    size_t off = 0;
    auto alloc = [&](size_t bytes){ size_t o = off; off += (bytes + 255) & ~(size_t)255; return o; };
    size_t o_counts = alloc(N_NODES*4);
    size_t o_cursor = alloc(N_NODES*4);
    size_t o_offs   = alloc((N_NODES+1)*4);
    size_t o_as     = alloc(N_NODES*HEADS*4);
    size_t o_ad     = alloc(N_NODES*HEADS*4);
    size_t o_invs   = alloc(N_NODES*HEADS*4);
    size_t o_dinv   = alloc(N_NODES*4);
    size_t o_srcs   = alloc(E_TOT*4);
    size_t o_dsts   = alloc(E_TOT*4);
    size_t o_esrt   = alloc((size_t)E_TOT*HEADS*4);
    size_t o_xh     = alloc((size_t)MPAD*KP_GAT*2);
    size_t o_xt     = alloc((size_t)MPAD*NP_GAT*2);
    size_t o_h1     = alloc((size_t)MPAD*KP_GCN*2);
    size_t o_xt2    = alloc((size_t)MPAD*KP_G1*2);
    size_t o_h2     = alloc((size_t)MPAD*KP_G1*2);
    size_t o_h3     = alloc((size_t)MPAD*KP_G2*2);
    size_t o_h4     = alloc((size_t)MPAD*F_G2*2);
    size_t o_wgatT  = alloc((size_t)NP_GAT*KP_GAT*2);
    size_t o_wgcnT  = alloc((size_t)NP_GCN*KP_GCN*2);
    size_t o_wg1T   = alloc((size_t)NP_G1*KP_G1*2);
    size_t o_wg2T   = alloc((size_t)NP_G2*KP_G2*2);

    int*    counts  = (int*)(ws + o_counts);
    int*    cursor  = (int*)(ws + o_cursor);
    int*    offsets = (int*)(ws + o_offs);
    float*  a_s     = (float*)(ws + o_as);
    float*  a_d     = (float*)(ws + o_ad);
    float*  inv_s   = (float*)(ws + o_invs);
    float*  dinv    = (float*)(ws + o_dinv);
    int*    src_srt = (int*)(ws + o_srcs);
    int*    dst_srt = (int*)(ws + o_dsts);
    float*  e_srt   = (float*)(ws + o_esrt);
    half_t* xh      = (half_t*)(ws + o_xh);
    half_t* xt_h    = (half_t*)(ws + o_xt);
    half_t* h1h     = (half_t*)(ws + o_h1);
    half_t* xt2_h   = (half_t*)(ws + o_xt2);
    half_t* h2h     = (half_t*)(ws + o_h2);
    half_t* h3h     = (half_t*)(ws + o_h3);
    half_t* h4h     = (half_t*)(ws + o_h4);
    half_t* WgatT   = (half_t*)(ws + o_wgatT);
    half_t* WgcnT   = (half_t*)(ws + o_wgcnT);
    half_t* Wg1T    = (half_t*)(ws + o_wg1T);
    half_t* Wg2T    = (half_t*)(ws + o_wg2T);

    /* CSR build */
    hipMemsetAsync(counts, 0, N_NODES*4, stream);
    hipMemsetAsync(cursor, 0, N_NODES*4, stream);
    k_count<<<(E_TOT+255)/256, 256, 0, stream>>>(ei, counts);
    k_scan<<<1, 256, 0, stream>>>(counts, offsets);
    k_fill<<<(E_TOT+255)/256, 256, 0, stream>>>(ei, offsets, cursor, src_srt, dst_srt);

    /* fp16 packing */
    k_xh<<<(MPAD*KP_GAT+255)/256, 256, 0, stream>>>(x, xh);
    k_wt<<<(NP_GAT*KP_GAT+255)/256, 256, 0, stream>>>(W_gat, WgatT, F_INPUT, F_GAT, KP_GAT, NP_GAT);
    k_wt<<<(NP_GCN*KP_GCN+255)/256, 256, 0, stream>>>(W_gcn, WgcnT, F_GAT, F_GCN, KP_GCN, NP_GCN);
    k_wt<<<(NP_G1*KP_G1+255)/256, 256, 0, stream>>>(W_g1, Wg1T, F_GCN, F_G1, KP_G1, NP_G1);
    k_wt<<<(NP_G2*KP_G2+255)/256, 256, 0, stream>>>(W_g2, Wg2T, F_G1, F_G2, KP_G2, NP_G2);

    /* GAT: xt = x @ W_gat (no bias/act) */
    k_hgemm<<<dim3(NP_GAT/128, MPAD/128), 256, 0, stream>>>(
        xh, WgatT, xt_h, nullptr, F_GAT, NP_GAT, KP_GAT, 1.0f);
    k_attn_ad<<<(N_NODES*HEADS+255)/256, 256, 0, stream>>>(xt_h, att_src, att_dst, a_s, a_d);
    k_edge<<<((size_t)E_TOT*HEADS+255)/256, 256, 0, stream>>>(src_srt, dst_srt, a_s, a_d, e_srt);
    k_softmax<<<(N_NODES*HEADS+255)/256, 256, 0, stream>>>(offsets, e_srt, inv_s);
    k_gat_agg<<<N_NODES, 256, 0, stream>>>(offsets, src_srt, e_srt, inv_s, xt_h, b_gat, h1h);

    /* GCN: xt2 = h1 @ W_gcn (no bias/act) */
    k_hgemm<<<dim3(NP_GCN/128, MPAD/128), 256, 0, stream>>>(
        h1h, WgcnT, xt2_h, nullptr, F_GCN, KP_G1, KP_GCN, 1.0f);
    k_dinv<<<(N_NODES+255)/256, 256, 0, stream>>>(offsets, dinv);
    k_gcn_agg<<<N_NODES, 256, 0, stream>>>(offsets, src_srt, dinv, xt2_h, b_gcn, h2h);

    /* g1: h3 = leaky(h2 @ W_g1 + b_g1) */
    k_hgemm<<<dim3(NP_G1/128, MPAD/128), 256, 0, stream>>>(
        h2h, Wg1T, h3h, b_g1, F_G1, KP_G2, KP_G1, 0.01f);
    /* g2: h4 = leaky(h3 @ W_g2 + b_g2) */
    k_hgemm<<<dim3(NP_G2/128, MPAD/128), 256, 0, stream>>>(
        h3h, Wg2T, h4h, b_g2, F_G2, F_G2, KP_G2, 0.01f);

    k_tail<<<N_NODES/8, 256, 0, stream>>>(h4h, W_fc1, b_fc1, W_fc2, b_fc2,
                                          W_out, b_out, out);
}

// Round 3
// 386.023 us; speedup vs baseline: 3.6512x; 1.2898x over previous
//
#include <hip/hip_runtime.h>
#include <hip/hip_bf16.h>
#include <math.h>

#define N_NODES 10000
#define MPAD    10112    /* 79*128 */
#define N_EDGESI 120000
#define E_TOT   130000   /* with self loops */
#define F_INPUT 66
#define HEADS   10
#define F_HEAD  66
#define F_GAT   660      /* HEADS*F_HEAD */
#define F_GCN   1320
#define F_G1    1000
#define F_G2    64

typedef _Float16 half_t;
typedef __attribute__((ext_vector_type(4))) _Float16 f16x4;
typedef __attribute__((ext_vector_type(8))) _Float16 f16x8;
typedef __attribute__((ext_vector_type(4))) float f32x4;

/* padded K / N for fp16 MFMA GEMMs (K mult of 64, N mult of 128) */
#define KP_GAT 128
#define NP_GAT 768
#define KP_GCN 704      /* = GAT output padded; also K of GCN GEMM */
#define NP_GCN 1408
#define KP_G1  1344
#define NP_G1  1024
#define KP_G2  1024
#define NP_G2  128

__device__ __forceinline__ float lky(float x, float s){ return x >= 0.f ? x : s*x; }

#if defined(__has_builtin)
#if __has_builtin(__builtin_amdgcn_global_load_lds)
#define HAVE_GLL 1
#endif
#endif

#ifdef HAVE_GLL
#define LDSLOAD16(g, l) __builtin_amdgcn_global_load_lds( \
    (const __attribute__((address_space(1))) void*)(g),   \
    (__attribute__((address_space(3))) void*)(l), 16, 0, 0)
#else
#define LDSLOAD16(g, l) (*(f16x8*)(l) = *(const f16x8*)(g))
#endif

/* ---------------- CSR build ---------------- */

__global__ void k_count(const int* __restrict__ ei, int* __restrict__ counts){
    int e = blockIdx.x*256 + threadIdx.x;
    if (e >= E_TOT) return;
    int dst = (e < N_EDGESI) ? ei[N_EDGESI + e] : (e - N_EDGESI);
    atomicAdd(&counts[dst], 1);
}

__global__ void k_scan(const int* __restrict__ counts, int* __restrict__ offsets){
    __shared__ int sh[256];
    int carry = 0;
    for (int base = 0; base < N_NODES; base += 256){
        int i = base + threadIdx.x;
        int v = (i < N_NODES) ? counts[i] : 0;
        sh[threadIdx.x] = v;
        __syncthreads();
        for (int off = 1; off < 256; off <<= 1){
            int t = (threadIdx.x >= off) ? sh[threadIdx.x - off] : 0;
            __syncthreads();
            sh[threadIdx.x] += t;
            __syncthreads();
        }
        if (i < N_NODES) offsets[i] = carry + sh[threadIdx.x] - v;
        int tot = sh[255];
        __syncthreads();
        carry += tot;
    }
    if (threadIdx.x == 0) offsets[N_NODES] = carry;
}

__global__ void k_fill(const int* __restrict__ ei, const int* __restrict__ offsets,
                       int* __restrict__ cursor, int* __restrict__ src_sorted){
    int e = blockIdx.x*256 + threadIdx.x;
    if (e >= E_TOT) return;
    int s, d;
    if (e < N_EDGESI){ s = ei[e]; d = ei[N_EDGESI + e]; }
    else { s = e - N_EDGESI; d = s; }
    int pos = offsets[d] + atomicAdd(&cursor[d], 1);
    src_sorted[pos] = s;
}

/* ---------------- fp32 -> fp16 packers ---------------- */

__global__ void k_xh(const float* __restrict__ x, half_t* __restrict__ xh){
    int idx = blockIdx.x*256 + threadIdx.x;
    if (idx >= MPAD*KP_GAT) return;
    int r = idx >> 7, c = idx & 127;
    float v = (r < N_NODES && c < F_INPUT) ? x[r*F_INPUT + c] : 0.f;
    xh[idx] = (half_t)v;
}

__global__ void k_wt(const float* __restrict__ W, half_t* __restrict__ WT,
                     int K, int N, int Kp, int Np){
    int idx = blockIdx.x*256 + threadIdx.x;
    if (idx >= Np*Kp) return;
    int n = idx / Kp, k = idx - n*Kp;
    float v = (n < N && k < K) ? W[(size_t)k*N + n] : 0.f;
    WT[idx] = (half_t)v;
}

/* ---------------- fp16 MFMA GEMM (m97-style 128x128, BK=64, XOR swizzle) */
__global__ __launch_bounds__(256)
void k_hgemm(const half_t* __restrict__ A, const half_t* __restrict__ Bt,
             half_t* __restrict__ C, const float* __restrict__ bias,
             int Nreal, int ldc, int Kp, float slope){
    __shared__ half_t As[128*64];
    __shared__ half_t Bs[128*64];
    const int tid = threadIdx.x;
    const int l = tid & 63;
    const int wid = tid >> 6;
    const int wr = wid >> 1, wc = wid & 1;
    const int brow = blockIdx.y * 128;
    const int bcol = blockIdx.x * 128;

    f32x4 acc[4][4] = {};

    for (int k0 = 0; k0 < Kp; k0 += 64){
        #pragma unroll
        for (int i = 0; i < 4; i++){
            int s = tid + i*256;          /* 16B slot index, 0..1023 */
            int row = s >> 3, chp = s & 7;
            int ch = chp ^ (row & 7);     /* inverse-swizzled source chunk */
            LDSLOAD16(A  + (size_t)(brow+row)*Kp + k0 + ch*8, &As[s*8]);
            LDSLOAD16(Bt + (size_t)(bcol+row)*Kp + k0 + ch*8, &Bs[s*8]);
        }
        __syncthreads();
        #pragma unroll
        for (int t = 0; t < 2; t++){
            f16x8 af[4], bf[4];
            #pragma unroll
            for (int m = 0; m < 4; m++){
                int row = wr*64 + m*16 + (l & 15);
                int ch = (t*4 + (l >> 4)) ^ (row & 7);
                af[m] = *(const f16x8*)&As[row*64 + ch*8];
            }
            #pragma unroll
            for (int n = 0; n < 4; n++){
                int row = wc*64 + n*16 + (l & 15);
                int ch = (t*4 + (l >> 4)) ^ (row & 7);
                bf[n] = *(const f16x8*)&Bs[row*64 + ch*8];
            }
            #pragma unroll
            for (int m = 0; m < 4; m++)
                #pragma unroll
                for (int n = 0; n < 4; n++)
                    acc[m][n] = __builtin_amdgcn_mfma_f32_16x16x32_f16(
                        af[m], bf[n], acc[m][n], 0, 0, 0);
        }
        __syncthreads();
    }

    #pragma unroll
    for (int m = 0; m < 4; m++){
        #pragma unroll
        for (int n = 0; n < 4; n++){
            int col = bcol + wc*64 + n*16 + (l & 15);
            if (col >= ldc) continue;
            float bv = (bias && col < Nreal) ? bias[col] : 0.f;
            #pragma unroll
            for (int r = 0; r < 4; r++){
                int rowg = brow + wr*64 + m*16 + ((l >> 4) << 2) + r;
                float v = (col < Nreal) ? acc[m][n][r] + bv : 0.f;
                v = (v >= 0.f) ? v : slope*v;
                C[(size_t)rowg*ldc + col] = (half_t)v;
            }
        }
    }
}

/* ---------------- GAT attention ---------------- */

__global__ void k_attn_ad(const half_t* __restrict__ xt,
                          const float* __restrict__ att_src, const float* __restrict__ att_dst,
                          float* __restrict__ a_s, float* __restrict__ a_d){
    int t = blockIdx.x*256 + threadIdx.x;
    if (t >= N_NODES*HEADS) return;
    int n = t / HEADS, h = t - (t/HEADS)*HEADS;
    const half_t* xr = xt + (size_t)n*NP_GAT + h*F_HEAD;
    const float* as = att_src + h*F_HEAD;
    const float* ad = att_dst + h*F_HEAD;
    float s = 0.f, d = 0.f;
    for (int f = 0; f < F_HEAD; f++){ float v = (float)xr[f]; s += v*as[f]; d += v*ad[f]; }
    a_s[t] = s; a_d[t] = d;
}

/* fused edge-score + segment softmax: one thread per (node, head) */
__global__ void k_softmax(const int* __restrict__ offsets, const int* __restrict__ src_sorted,
                          const float* __restrict__ a_s, const float* __restrict__ a_d,
                          float* __restrict__ e_sorted, float* __restrict__ inv_s){
    int t = blockIdx.x*256 + threadIdx.x;
    if (t >= N_NODES*HEADS) return;
    int n = t / HEADS, h = t - (t/HEADS)*HEADS;
    int b = offsets[n], e = offsets[n+1];
    float ad_n = a_d[t - h + h];  /* a_d[n*HEADS+h] == a_d[t] */
    ad_n = a_d[t];
    float m = -INFINITY;
    for (int s = b; s < e; s++){
        float v = lky(a_s[src_sorted[s]*HEADS + h] + ad_n, 0.2f);
        e_sorted[(size_t)s*HEADS + h] = v;
        m = fmaxf(m, v);
    }
    float sum = 0.f;
    for (int s = b; s < e; s++){
        float ex = __expf(e_sorted[(size_t)s*HEADS + h] - m);
        e_sorted[(size_t)s*HEADS + h] = ex;
        sum += ex;
    }
    inv_s[t] = 1.0f / fmaxf(sum, 1e-16f);
}

/* GAT aggregation: block(192) per node, f16x4 per thread over 768-padded xt rows.
   inv_s factor hoisted out of the edge loop; writes h1 rows padded to 704. */
__global__ __launch_bounds__(192)
void k_gat_agg(const int* __restrict__ offsets, const int* __restrict__ src_sorted,
               const float* __restrict__ e_sorted, const float* __restrict__ inv_s,
               const half_t* __restrict__ xt, const float* __restrict__ b_gat,
               half_t* __restrict__ out){
    int n = blockIdx.x, t = threadIdx.x;
    int f0 = 4*t;
    int h0 = min(f0/F_HEAD, HEADS-1);
    int h1 = min((f0+1)/F_HEAD, HEADS-1);
    int h2 = min((f0+2)/F_HEAD, HEADS-1);
    int h3 = min((f0+3)/F_HEAD, HEADS-1);
    int b = offsets[n], e = offsets[n+1];
    float a0=0.f, a1=0.f, a2=0.f, a3=0.f;
    int s = b;
    for (; s + 2 <= e; s += 2){
        int s0 = src_sorted[s], s1 = src_sorted[s+1];
        f16x4 v0 = *(const f16x4*)(xt + (size_t)s0*NP_GAT + f0);
        f16x4 v1 = *(const f16x4*)(xt + (size_t)s1*NP_GAT + f0);
        const float* e0 = e_sorted + (size_t)s*HEADS;
        const float* e1 = e0 + HEADS;
        a0 += e0[h0]*(float)v0.x + e1[h0]*(float)v1.x;
        a1 += e0[h1]*(float)v0.y + e1[h1]*(float)v1.y;
        a2 += e0[h2]*(float)v0.z + e1[h2]*(float)v1.z;
        a3 += e0[h3]*(float)v0.w + e1[h3]*(float)v1.w;
    }
    if (s < e){
        int s0 = src_sorted[s];
        f16x4 v0 = *(const f16x4*)(xt + (size_t)s0*NP_GAT + f0);
        const float* e0 = e_sorted + (size_t)s*HEADS;
        a0 += e0[h0]*(float)v0.x;
        a1 += e0[h1]*(float)v0.y;
        a2 += e0[h2]*(float)v0.z;
        a3 += e0[h3]*(float)v0.w;
    }
    if (f0 >= KP_GCN) return;        /* t >= 176 */
    half_t* orow = out + (size_t)n*KP_GCN + f0;
    if (f0 < F_GAT){                 /* 660 % 4 == 0: no straddle */
        const float* iv = inv_s + n*HEADS;
        f16x4 r;
        r.x = (half_t)lky(a0*iv[h0] + b_gat[f0  ], 0.01f);
        r.y = (half_t)lky(a1*iv[h1] + b_gat[f0+1], 0.01f);
        r.z = (half_t)lky(a2*iv[h2] + b_gat[f0+2], 0.01f);
        r.w = (half_t)lky(a3*iv[h3] + b_gat[f0+3], 0.01f);
        *(f16x4*)orow = r;
    } else {
        f16x4 z = {(half_t)0.f,(half_t)0.f,(half_t)0.f,(half_t)0.f};
        *(f16x4*)orow = z;
    }
}

/* ---------------- GCN (aggregate-first) ---------------- */

__global__ void k_dinv(const int* __restrict__ offsets, float* __restrict__ dinv){
    int n = blockIdx.x*256 + threadIdx.x;
    if (n >= N_NODES) return;
    float deg = (float)(offsets[n+1] - offsets[n]);
    dinv[n] = rsqrtf(fmaxf(deg, 1.0f));
}

/* agg[n] = dinv[n] * sum_{s in N(n)} dinv[src] * h1[src]  (660 feats, 704 padded) */
__global__ __launch_bounds__(192)
void k_gcn_pre(const int* __restrict__ offsets, const int* __restrict__ src_sorted,
               const float* __restrict__ dinv, const half_t* __restrict__ h1,
               half_t* __restrict__ agg){
    int n = blockIdx.x, t = threadIdx.x;
    if (t >= 176) return;            /* 176*4 = 704 */
    int f0 = 4*t;
    int b = offsets[n], e = offsets[n+1];
    float a0=0.f, a1=0.f, a2=0.f, a3=0.f;
    int s = b;
    for (; s + 2 <= e; s += 2){
        int s0 = src_sorted[s], s1 = src_sorted[s+1];
        float n0 = dinv[s0], n1 = dinv[s1];
        f16x4 v0 = *(const f16x4*)(h1 + (size_t)s0*KP_GCN + f0);
        f16x4 v1 = *(const f16x4*)(h1 + (size_t)s1*KP_GCN + f0);
        a0 += n0*(float)v0.x + n1*(float)v1.x;
        a1 += n0*(float)v0.y + n1*(float)v1.y;
        a2 += n0*(float)v0.z + n1*(float)v1.z;
        a3 += n0*(float)v0.w + n1*(float)v1.w;
    }
    if (s < e){
        int s0 = src_sorted[s];
        float n0 = dinv[s0];
        f16x4 v0 = *(const f16x4*)(h1 + (size_t)s0*KP_GCN + f0);
        a0 += n0*(float)v0.x;
        a1 += n0*(float)v0.y;
        a2 += n0*(float)v0.z;
        a3 += n0*(float)v0.w;
    }
    float dn = dinv[n];
    f16x4 r;
    r.x = (half_t)(dn*a0); r.y = (half_t)(dn*a1);
    r.z = (half_t)(dn*a2); r.w = (half_t)(dn*a3);
    *(f16x4*)(agg + (size_t)n*KP_GCN + f0) = r;
}

/* ---------------- fused tail MLP: 64->32->16->1 ---------------- */
__global__ __launch_bounds__(256)
void k_tail(const half_t* __restrict__ h4,
            const float* __restrict__ Wfc1, const float* __restrict__ bfc1,
            const float* __restrict__ Wfc2, const float* __restrict__ bfc2,
            const float* __restrict__ Wout, const float* __restrict__ bout,
            float* __restrict__ out){
    __shared__ float W1[64*32];
    __shared__ float W2[32*16];
    __shared__ float Wo[16];
    __shared__ float b1[32];
    __shared__ float b2[16];
    __shared__ float r1[8][32];
    __shared__ float r2[8][16];
    int tid = threadIdx.x;
    for (int i = tid; i < 64*32; i += 256) W1[i] = Wfc1[i];
    for (int i = tid; i < 32*16; i += 256) W2[i] = Wfc2[i];
    if (tid < 16) Wo[tid] = Wout[tid];
    if (tid < 32) b1[tid] = bfc1[tid];
    if (tid < 16) b2[tid] = bfc2[tid];
    __syncthreads();
    int g = tid >> 5, j = tid & 31;
    int node = blockIdx.x*8 + g;
    const half_t* hr = h4 + (size_t)node*F_G2;
    float acc = 0.f;
    #pragma unroll 8
    for (int i = 0; i < 64; i++) acc += (float)hr[i]*W1[i*32 + j];
    r1[g][j] = lky(acc + b1[j], 0.01f);
    __syncthreads();
    if (j < 16){
        float a2 = 0.f;
        #pragma unroll
        for (int i = 0; i < 32; i++) a2 += r1[g][i]*W2[i*16 + j];
        r2[g][j] = lky(a2 + b2[j], 0.01f);
    }
    __syncthreads();
    if (j == 0){
        float a3 = 0.f;
        #pragma unroll
        for (int i = 0; i < 16; i++) a3 += r2[g][i]*Wo[i];
        out[node] = a3 + bout[0];
    }
}

/* ---------------- launch ---------------- */

extern "C" void kernel_launch(void* const* d_in, const int* in_sizes, int n_in,
                              void* d_out, int out_size, void* d_ws, size_t ws_size,
                              hipStream_t stream){
    const float* x       = (const float*)d_in[0];
    const int*   ei      = (const int*)  d_in[1];
    const float* W_gat   = (const float*)d_in[2];
    const float* att_src = (const float*)d_in[3];
    const float* att_dst = (const float*)d_in[4];
    const float* b_gat   = (const float*)d_in[5];
    const float* W_gcn   = (const float*)d_in[6];
    const float* b_gcn   = (const float*)d_in[7];
    const float* W_g1    = (const float*)d_in[8];
    const float* b_g1    = (const float*)d_in[9];
    const float* W_g2    = (const float*)d_in[10];
    const float* b_g2    = (const float*)d_in[11];
    const float* W_fc1   = (const float*)d_in[12];
    const float* b_fc1   = (const float*)d_in[13];
    const float* W_fc2   = (const float*)d_in[14];
    const float* b_fc2   = (const float*)d_in[15];
    const float* W_out   = (const float*)d_in[16];
    const float* b_out   = (const float*)d_in[17];
    float* out = (float*)d_out;
    char* ws = (char*)d_ws;

    size_t off = 0;
    auto alloc = [&](size_t bytes){ size_t o = off; off += (bytes + 255) & ~(size_t)255; return o; };
    size_t o_counts = alloc(N_NODES*4);
    size_t o_cursor = alloc(N_NODES*4);
    size_t o_offs   = alloc((N_NODES+1)*4);
    size_t o_as     = alloc(N_NODES*HEADS*4);
    size_t o_ad     = alloc(N_NODES*HEADS*4);
    size_t o_invs   = alloc(N_NODES*HEADS*4);
    size_t o_dinv   = alloc(N_NODES*4);
    size_t o_srcs   = alloc(E_TOT*4);
    size_t o_esrt   = alloc((size_t)E_TOT*HEADS*4);
    size_t o_xh     = alloc((size_t)MPAD*KP_GAT*2);
    size_t o_xt     = alloc((size_t)MPAD*NP_GAT*2);
    size_t o_h1     = alloc((size_t)N_NODES*KP_GCN*2);
    size_t o_agg    = alloc((size_t)MPAD*KP_GCN*2);
    size_t o_h2     = alloc((size_t)MPAD*KP_G1*2);
    size_t o_h3     = alloc((size_t)MPAD*KP_G2*2);
    size_t o_h4     = alloc((size_t)MPAD*F_G2*2);
    size_t o_wgatT  = alloc((size_t)NP_GAT*KP_GAT*2);
    size_t o_wgcnT  = alloc((size_t)NP_GCN*KP_GCN*2);
    size_t o_wg1T   = alloc((size_t)NP_G1*KP_G1*2);
    size_t o_wg2T   = alloc((size_t)NP_G2*KP_G2*2);

    int*    counts  = (int*)(ws + o_counts);
    int*    cursor  = (int*)(ws + o_cursor);
    int*    offsets = (int*)(ws + o_offs);
    float*  a_s     = (float*)(ws + o_as);
    float*  a_d     = (float*)(ws + o_ad);
    float*  inv_s   = (float*)(ws + o_invs);
    float*  dinv    = (float*)(ws + o_dinv);
    int*    src_srt = (int*)(ws + o_srcs);
    float*  e_srt   = (float*)(ws + o_esrt);
    half_t* xh      = (half_t*)(ws + o_xh);
    half_t* xt_h    = (half_t*)(ws + o_xt);
    half_t* h1h     = (half_t*)(ws + o_h1);
    half_t* aggh    = (half_t*)(ws + o_agg);
    half_t* h2h     = (half_t*)(ws + o_h2);
    half_t* h3h     = (half_t*)(ws + o_h3);
    half_t* h4h     = (half_t*)(ws + o_h4);
    half_t* WgatT   = (half_t*)(ws + o_wgatT);
    half_t* WgcnT   = (half_t*)(ws + o_wgcnT);
    half_t* Wg1T    = (half_t*)(ws + o_wg1T);
    half_t* Wg2T    = (half_t*)(ws + o_wg2T);

    /* CSR build */
    hipMemsetAsync(counts, 0, N_NODES*4, stream);
    hipMemsetAsync(cursor, 0, N_NODES*4, stream);
    k_count<<<(E_TOT+255)/256, 256, 0, stream>>>(ei, counts);
    k_scan<<<1, 256, 0, stream>>>(counts, offsets);
    k_fill<<<(E_TOT+255)/256, 256, 0, stream>>>(ei, offsets, cursor, src_srt);
    k_dinv<<<(N_NODES+255)/256, 256, 0, stream>>>(offsets, dinv);

    /* fp16 packing */
    k_xh<<<(MPAD*KP_GAT+255)/256, 256, 0, stream>>>(x, xh);
    k_wt<<<(NP_GAT*KP_GAT+255)/256, 256, 0, stream>>>(W_gat, WgatT, F_INPUT, F_GAT, KP_GAT, NP_GAT);
    k_wt<<<(NP_GCN*KP_GCN+255)/256, 256, 0, stream>>>(W_gcn, WgcnT, F_GAT, F_GCN, KP_GCN, NP_GCN);
    k_wt<<<(NP_G1*KP_G1+255)/256, 256, 0, stream>>>(W_g1, Wg1T, F_GCN, F_G1, KP_G1, NP_G1);
    k_wt<<<(NP_G2*KP_G2+255)/256, 256, 0, stream>>>(W_g2, Wg2T, F_G1, F_G2, KP_G2, NP_G2);

    /* GAT: xt = x @ W_gat */
    k_hgemm<<<dim3(NP_GAT/128, MPAD/128), 256, 0, stream>>>(
        xh, WgatT, xt_h, nullptr, F_GAT, NP_GAT, KP_GAT, 1.0f);
    k_attn_ad<<<(N_NODES*HEADS+255)/256, 256, 0, stream>>>(xt_h, att_src, att_dst, a_s, a_d);
    k_softmax<<<(N_NODES*HEADS+255)/256, 256, 0, stream>>>(offsets, src_srt, a_s, a_d, e_srt, inv_s);
    k_gat_agg<<<N_NODES, 192, 0, stream>>>(offsets, src_srt, e_srt, inv_s, xt_h, b_gat, h1h);

    /* GCN aggregate-first: agg = D^-1/2 A D^-1/2 h1, then GEMM w/ fused bias+leaky */
    k_gcn_pre<<<N_NODES, 192, 0, stream>>>(offsets, src_srt, dinv, h1h, aggh);
    k_hgemm<<<dim3(NP_GCN/128, MPAD/128), 256, 0, stream>>>(
        aggh, WgcnT, h2h, b_gcn, F_GCN, KP_G1, KP_GCN, 0.01f);

    /* dense tail */
    k_hgemm<<<dim3(NP_G1/128, MPAD/128), 256, 0, stream>>>(
        h2h, Wg1T, h3h, b_g1, F_G1, KP_G2, KP_G1, 0.01f);
    k_hgemm<<<dim3(NP_G2/128, MPAD/128), 256, 0, stream>>>(
        h3h, Wg2T, h4h, b_g2, F_G2, F_G2, KP_G2, 0.01f);
    k_tail<<<N_NODES/8, 256, 0, stream>>>(h4h, W_fc1, b_fc1, W_fc2, b_fc2,
                                          W_out, b_out, out);
}

// Round 4
// 380.672 us; speedup vs baseline: 3.7026x; 1.0141x over previous
//
#include <hip/hip_runtime.h>
#include <hip/hip_bf16.h>
#include <math.h>

#define N_NODES 10000
#define MPAD    10112    /* 79*128 */
#define N_EDGESI 120000
#define E_TOT   130000   /* with self loops */
#define F_INPUT 66
#define HEADS   10
#define F_HEAD  66
#define F_GAT   660      /* HEADS*F_HEAD */
#define F_GCN   1320
#define F_G1    1000
#define F_G2    64

typedef _Float16 half_t;
typedef __attribute__((ext_vector_type(2))) _Float16 f16x2;
typedef __attribute__((ext_vector_type(4))) _Float16 f16x4;
typedef __attribute__((ext_vector_type(8))) _Float16 f16x8;
typedef __attribute__((ext_vector_type(4))) float f32x4;

/* padded K / N for fp16 MFMA GEMMs (K mult of 64, N mult of 128) */
#define KP_GAT 128
#define NP_GAT 768
#define KP_GCN 704      /* = GAT output padded; also K of GCN GEMM */
#define NP_GCN 1408
#define KP_G1  1344
#define NP_G1  1024
#define KP_G2  1024
#define NP_G2  128

__device__ __forceinline__ float lky(float x, float s){ return x >= 0.f ? x : s*x; }

#if defined(__has_builtin)
#if __has_builtin(__builtin_amdgcn_global_load_lds)
#define HAVE_GLL 1
#endif
#endif

#ifdef HAVE_GLL
#define LDSLOAD16(g, l) __builtin_amdgcn_global_load_lds( \
    (const __attribute__((address_space(1))) void*)(g),   \
    (__attribute__((address_space(3))) void*)(l), 16, 0, 0)
#else
#define LDSLOAD16(g, l) (*(f16x8*)(l) = *(const f16x8*)(g))
#endif

/* ---------------- CSR build ---------------- */

__global__ void k_count(const int* __restrict__ ei, int* __restrict__ counts){
    int e = blockIdx.x*256 + threadIdx.x;
    if (e >= E_TOT) return;
    int dst = (e < N_EDGESI) ? ei[N_EDGESI + e] : (e - N_EDGESI);
    atomicAdd(&counts[dst], 1);
}

__global__ void k_scan(const int* __restrict__ counts, int* __restrict__ offsets){
    __shared__ int sh[256];
    int carry = 0;
    for (int base = 0; base < N_NODES; base += 256){
        int i = base + threadIdx.x;
        int v = (i < N_NODES) ? counts[i] : 0;
        sh[threadIdx.x] = v;
        __syncthreads();
        for (int off = 1; off < 256; off <<= 1){
            int t = (threadIdx.x >= off) ? sh[threadIdx.x - off] : 0;
            __syncthreads();
            sh[threadIdx.x] += t;
            __syncthreads();
        }
        if (i < N_NODES) offsets[i] = carry + sh[threadIdx.x] - v;
        int tot = sh[255];
        __syncthreads();
        carry += tot;
    }
    if (threadIdx.x == 0) offsets[N_NODES] = carry;
}

__global__ void k_fill(const int* __restrict__ ei, const int* __restrict__ offsets,
                       int* __restrict__ cursor, int* __restrict__ src_sorted){
    int e = blockIdx.x*256 + threadIdx.x;
    if (e >= E_TOT) return;
    int s, d;
    if (e < N_EDGESI){ s = ei[e]; d = ei[N_EDGESI + e]; }
    else { s = e - N_EDGESI; d = s; }
    int pos = offsets[d] + atomicAdd(&cursor[d], 1);
    src_sorted[pos] = s;
}

/* ---------------- fp32 -> fp16 packers ---------------- */

__global__ void k_xh(const float* __restrict__ x, half_t* __restrict__ xh){
    int idx = blockIdx.x*256 + threadIdx.x;
    if (idx >= MPAD*KP_GAT) return;
    int r = idx >> 7, c = idx & 127;
    float v = (r < N_NODES && c < F_INPUT) ? x[r*F_INPUT + c] : 0.f;
    xh[idx] = (half_t)v;
}

__global__ void k_wt(const float* __restrict__ W, half_t* __restrict__ WT,
                     int K, int N, int Kp, int Np){
    int idx = blockIdx.x*256 + threadIdx.x;
    if (idx >= Np*Kp) return;
    int n = idx / Kp, k = idx - n*Kp;
    float v = (n < N && k < K) ? W[(size_t)k*N + n] : 0.f;
    WT[idx] = (half_t)v;
}

/* ---------------- fp16 MFMA GEMM (m97-style 128x128, BK=64, XOR swizzle)
   + bijective XCD block swizzle (m204): consecutive dispatch-order blocks
   share an A row-panel; mapping each XCD a contiguous wgid chunk keeps the
   panel in one L2 instead of being fetched by all 8. */
__global__ __launch_bounds__(256)
void k_hgemm(const half_t* __restrict__ A, const half_t* __restrict__ Bt,
             half_t* __restrict__ C, const float* __restrict__ bias,
             int Nreal, int ldc, int Kp, float slope){
    __shared__ half_t As[128*64];
    __shared__ half_t Bs[128*64];
    const int tid = threadIdx.x;
    const int l = tid & 63;
    const int wid = tid >> 6;
    const int wr = wid >> 1, wc = wid & 1;

    /* XCD-aware bijective remap */
    const int gx = gridDim.x;
    const int nwg = gx * gridDim.y;
    const int orig = blockIdx.y * gx + blockIdx.x;
    const int q = nwg >> 3, r8 = nwg & 7;
    const int xcd = orig & 7, lin = orig >> 3;
    const int wgid = (xcd < r8 ? xcd*(q+1) : r8*(q+1) + (xcd-r8)*q) + lin;
    const int bx = wgid % gx, by = wgid / gx;

    const int brow = by * 128;
    const int bcol = bx * 128;

    f32x4 acc[4][4] = {};

    for (int k0 = 0; k0 < Kp; k0 += 64){
        #pragma unroll
        for (int i = 0; i < 4; i++){
            int s = tid + i*256;          /* 16B slot index, 0..1023 */
            int row = s >> 3, chp = s & 7;
            int ch = chp ^ (row & 7);     /* inverse-swizzled source chunk */
            LDSLOAD16(A  + (size_t)(brow+row)*Kp + k0 + ch*8, &As[s*8]);
            LDSLOAD16(Bt + (size_t)(bcol+row)*Kp + k0 + ch*8, &Bs[s*8]);
        }
        __syncthreads();
        #pragma unroll
        for (int t = 0; t < 2; t++){
            f16x8 af[4], bf[4];
            #pragma unroll
            for (int m = 0; m < 4; m++){
                int row = wr*64 + m*16 + (l & 15);
                int ch = (t*4 + (l >> 4)) ^ (row & 7);
                af[m] = *(const f16x8*)&As[row*64 + ch*8];
            }
            #pragma unroll
            for (int n = 0; n < 4; n++){
                int row = wc*64 + n*16 + (l & 15);
                int ch = (t*4 + (l >> 4)) ^ (row & 7);
                bf[n] = *(const f16x8*)&Bs[row*64 + ch*8];
            }
            #pragma unroll
            for (int m = 0; m < 4; m++)
                #pragma unroll
                for (int n = 0; n < 4; n++)
                    acc[m][n] = __builtin_amdgcn_mfma_f32_16x16x32_f16(
                        af[m], bf[n], acc[m][n], 0, 0, 0);
        }
        __syncthreads();
    }

    #pragma unroll
    for (int m = 0; m < 4; m++){
        #pragma unroll
        for (int n = 0; n < 4; n++){
            int col = bcol + wc*64 + n*16 + (l & 15);
            if (col >= ldc) continue;
            float bv = (bias && col < Nreal) ? bias[col] : 0.f;
            #pragma unroll
            for (int r = 0; r < 4; r++){
                int rowg = brow + wr*64 + m*16 + ((l >> 4) << 2) + r;
                float v = (col < Nreal) ? acc[m][n][r] + bv : 0.f;
                v = (v >= 0.f) ? v : slope*v;
                C[(size_t)rowg*ldc + col] = (half_t)v;
            }
        }
    }
}

/* ---------------- GAT attention ---------------- */

__global__ void k_attn_ad(const half_t* __restrict__ xt,
                          const float* __restrict__ att_src, const float* __restrict__ att_dst,
                          float* __restrict__ a_s, float* __restrict__ a_d){
    int t = blockIdx.x*256 + threadIdx.x;
    if (t >= N_NODES*HEADS) return;
    int n = t / HEADS, h = t - (t/HEADS)*HEADS;
    const half_t* xr = xt + (size_t)n*NP_GAT + h*F_HEAD;   /* 4B aligned (66h even) */
    const float* as = att_src + h*F_HEAD;
    const float* ad = att_dst + h*F_HEAD;
    float s = 0.f, d = 0.f;
    #pragma unroll
    for (int f = 0; f < F_HEAD; f += 2){
        f16x2 v = *(const f16x2*)(xr + f);
        float vx = (float)v.x, vy = (float)v.y;
        s += vx*as[f] + vy*as[f+1];
        d += vx*ad[f] + vy*ad[f+1];
    }
    a_s[t] = s; a_d[t] = d;
}

/* fused edge-score + segment softmax: one thread per (node, head) */
__global__ void k_softmax(const int* __restrict__ offsets, const int* __restrict__ src_sorted,
                          const float* __restrict__ a_s, const float* __restrict__ a_d,
                          float* __restrict__ e_sorted, float* __restrict__ inv_s){
    int t = blockIdx.x*256 + threadIdx.x;
    if (t >= N_NODES*HEADS) return;
    int n = t / HEADS, h = t - (t/HEADS)*HEADS;
    int b = offsets[n], e = offsets[n+1];
    float ad_n = a_d[t];
    float m = -INFINITY;
    for (int s = b; s < e; s++){
        float v = lky(a_s[src_sorted[s]*HEADS + h] + ad_n, 0.2f);
        e_sorted[(size_t)s*HEADS + h] = v;
        m = fmaxf(m, v);
    }
    float sum = 0.f;
    for (int s = b; s < e; s++){
        float ex = __expf(e_sorted[(size_t)s*HEADS + h] - m);
        e_sorted[(size_t)s*HEADS + h] = ex;
        sum += ex;
    }
    inv_s[t] = 1.0f / fmaxf(sum, 1e-16f);
}

/* GAT aggregation: block(192) per node, f16x4 per thread, edge loop unrolled x4 */
__global__ __launch_bounds__(192)
void k_gat_agg(const int* __restrict__ offsets, const int* __restrict__ src_sorted,
               const float* __restrict__ e_sorted, const float* __restrict__ inv_s,
               const half_t* __restrict__ xt, const float* __restrict__ b_gat,
               half_t* __restrict__ out){
    int n = blockIdx.x, t = threadIdx.x;
    int f0 = 4*t;
    int h0 = min(f0/F_HEAD, HEADS-1);
    int h1 = min((f0+1)/F_HEAD, HEADS-1);
    int h2 = min((f0+2)/F_HEAD, HEADS-1);
    int h3 = min((f0+3)/F_HEAD, HEADS-1);
    int b = offsets[n], e = offsets[n+1];
    float a0=0.f, a1=0.f, a2=0.f, a3=0.f;
    int s = b;
    for (; s + 4 <= e; s += 4){
        int s0 = src_sorted[s],   s1 = src_sorted[s+1];
        int s2 = src_sorted[s+2], s3 = src_sorted[s+3];
        f16x4 v0 = *(const f16x4*)(xt + (size_t)s0*NP_GAT + f0);
        f16x4 v1 = *(const f16x4*)(xt + (size_t)s1*NP_GAT + f0);
        f16x4 v2 = *(const f16x4*)(xt + (size_t)s2*NP_GAT + f0);
        f16x4 v3 = *(const f16x4*)(xt + (size_t)s3*NP_GAT + f0);
        const float* e0 = e_sorted + (size_t)s*HEADS;
        const float* e1 = e0 + HEADS;
        const float* e2 = e0 + 2*HEADS;
        const float* e3 = e0 + 3*HEADS;
        a0 += e0[h0]*(float)v0.x + e1[h0]*(float)v1.x + e2[h0]*(float)v2.x + e3[h0]*(float)v3.x;
        a1 += e0[h1]*(float)v0.y + e1[h1]*(float)v1.y + e2[h1]*(float)v2.y + e3[h1]*(float)v3.y;
        a2 += e0[h2]*(float)v0.z + e1[h2]*(float)v1.z + e2[h2]*(float)v2.z + e3[h2]*(float)v3.z;
        a3 += e0[h3]*(float)v0.w + e1[h3]*(float)v1.w + e2[h3]*(float)v2.w + e3[h3]*(float)v3.w;
    }
    for (; s < e; s++){
        int s0 = src_sorted[s];
        f16x4 v0 = *(const f16x4*)(xt + (size_t)s0*NP_GAT + f0);
        const float* e0 = e_sorted + (size_t)s*HEADS;
        a0 += e0[h0]*(float)v0.x;
        a1 += e0[h1]*(float)v0.y;
        a2 += e0[h2]*(float)v0.z;
        a3 += e0[h3]*(float)v0.w;
    }
    if (f0 >= KP_GCN) return;        /* t >= 176 */
    half_t* orow = out + (size_t)n*KP_GCN + f0;
    if (f0 < F_GAT){                 /* 660 % 4 == 0: no straddle */
        const float* iv = inv_s + n*HEADS;
        f16x4 r;
        r.x = (half_t)lky(a0*iv[h0] + b_gat[f0  ], 0.01f);
        r.y = (half_t)lky(a1*iv[h1] + b_gat[f0+1], 0.01f);
        r.z = (half_t)lky(a2*iv[h2] + b_gat[f0+2], 0.01f);
        r.w = (half_t)lky(a3*iv[h3] + b_gat[f0+3], 0.01f);
        *(f16x4*)orow = r;
    } else {
        f16x4 z = {(half_t)0.f,(half_t)0.f,(half_t)0.f,(half_t)0.f};
        *(f16x4*)orow = z;
    }
}

/* ---------------- GCN (aggregate-first) ---------------- */

__global__ void k_dinv(const int* __restrict__ offsets, float* __restrict__ dinv){
    int n = blockIdx.x*256 + threadIdx.x;
    if (n >= N_NODES) return;
    float deg = (float)(offsets[n+1] - offsets[n]);
    dinv[n] = rsqrtf(fmaxf(deg, 1.0f));
}

/* agg[n] = dinv[n] * sum_{s in N(n)} dinv[src] * h1[src], edge loop unrolled x4 */
__global__ __launch_bounds__(192)
void k_gcn_pre(const int* __restrict__ offsets, const int* __restrict__ src_sorted,
               const float* __restrict__ dinv, const half_t* __restrict__ h1,
               half_t* __restrict__ agg){
    int n = blockIdx.x, t = threadIdx.x;
    if (t >= 176) return;            /* 176*4 = 704 */
    int f0 = 4*t;
    int b = offsets[n], e = offsets[n+1];
    float a0=0.f, a1=0.f, a2=0.f, a3=0.f;
    int s = b;
    for (; s + 4 <= e; s += 4){
        int s0 = src_sorted[s],   s1 = src_sorted[s+1];
        int s2 = src_sorted[s+2], s3 = src_sorted[s+3];
        float n0 = dinv[s0], n1 = dinv[s1], n2 = dinv[s2], n3 = dinv[s3];
        f16x4 v0 = *(const f16x4*)(h1 + (size_t)s0*KP_GCN + f0);
        f16x4 v1 = *(const f16x4*)(h1 + (size_t)s1*KP_GCN + f0);
        f16x4 v2 = *(const f16x4*)(h1 + (size_t)s2*KP_GCN + f0);
        f16x4 v3 = *(const f16x4*)(h1 + (size_t)s3*KP_GCN + f0);
        a0 += n0*(float)v0.x + n1*(float)v1.x + n2*(float)v2.x + n3*(float)v3.x;
        a1 += n0*(float)v0.y + n1*(float)v1.y + n2*(float)v2.y + n3*(float)v3.y;
        a2 += n0*(float)v0.z + n1*(float)v1.z + n2*(float)v2.z + n3*(float)v3.z;
        a3 += n0*(float)v0.w + n1*(float)v1.w + n2*(float)v2.w + n3*(float)v3.w;
    }
    for (; s < e; s++){
        int s0 = src_sorted[s];
        float n0 = dinv[s0];
        f16x4 v0 = *(const f16x4*)(h1 + (size_t)s0*KP_GCN + f0);
        a0 += n0*(float)v0.x;
        a1 += n0*(float)v0.y;
        a2 += n0*(float)v0.z;
        a3 += n0*(float)v0.w;
    }
    float dn = dinv[n];
    f16x4 r;
    r.x = (half_t)(dn*a0); r.y = (half_t)(dn*a1);
    r.z = (half_t)(dn*a2); r.w = (half_t)(dn*a3);
    *(f16x4*)(agg + (size_t)n*KP_GCN + f0) = r;
}

/* ---------------- fused tail MLP: 64->32->16->1 ---------------- */
__global__ __launch_bounds__(256)
void k_tail(const half_t* __restrict__ h4,
            const float* __restrict__ Wfc1, const float* __restrict__ bfc1,
            const float* __restrict__ Wfc2, const float* __restrict__ bfc2,
            const float* __restrict__ Wout, const float* __restrict__ bout,
            float* __restrict__ out){
    __shared__ float W1[64*32];
    __shared__ float W2[32*16];
    __shared__ float Wo[16];
    __shared__ float b1[32];
    __shared__ float b2[16];
    __shared__ float r1[8][32];
    __shared__ float r2[8][16];
    int tid = threadIdx.x;
    for (int i = tid; i < 64*32; i += 256) W1[i] = Wfc1[i];
    for (int i = tid; i < 32*16; i += 256) W2[i] = Wfc2[i];
    if (tid < 16) Wo[tid] = Wout[tid];
    if (tid < 32) b1[tid] = bfc1[tid];
    if (tid < 16) b2[tid] = bfc2[tid];
    __syncthreads();
    int g = tid >> 5, j = tid & 31;
    int node = blockIdx.x*8 + g;
    const half_t* hr = h4 + (size_t)node*F_G2;
    float acc = 0.f;
    #pragma unroll 8
    for (int i = 0; i < 64; i++) acc += (float)hr[i]*W1[i*32 + j];
    r1[g][j] = lky(acc + b1[j], 0.01f);
    __syncthreads();
    if (j < 16){
        float a2 = 0.f;
        #pragma unroll
        for (int i = 0; i < 32; i++) a2 += r1[g][i]*W2[i*16 + j];
        r2[g][j] = lky(a2 + b2[j], 0.01f);
    }
    __syncthreads();
    if (j == 0){
        float a3 = 0.f;
        #pragma unroll
        for (int i = 0; i < 16; i++) a3 += r2[g][i]*Wo[i];
        out[node] = a3 + bout[0];
    }
}

/* ---------------- launch ---------------- */

extern "C" void kernel_launch(void* const* d_in, const int* in_sizes, int n_in,
                              void* d_out, int out_size, void* d_ws, size_t ws_size,
                              hipStream_t stream){
    const float* x       = (const float*)d_in[0];
    const int*   ei      = (const int*)  d_in[1];
    const float* W_gat   = (const float*)d_in[2];
    const float* att_src = (const float*)d_in[3];
    const float* att_dst = (const float*)d_in[4];
    const float* b_gat   = (const float*)d_in[5];
    const float* W_gcn   = (const float*)d_in[6];
    const float* b_gcn   = (const float*)d_in[7];
    const float* W_g1    = (const float*)d_in[8];
    const float* b_g1    = (const float*)d_in[9];
    const float* W_g2    = (const float*)d_in[10];
    const float* b_g2    = (const float*)d_in[11];
    const float* W_fc1   = (const float*)d_in[12];
    const float* b_fc1   = (const float*)d_in[13];
    const float* W_fc2   = (const float*)d_in[14];
    const float* b_fc2   = (const float*)d_in[15];
    const float* W_out   = (const float*)d_in[16];
    const float* b_out   = (const float*)d_in[17];
    float* out = (float*)d_out;
    char* ws = (char*)d_ws;

    size_t off = 0;
    auto alloc = [&](size_t bytes){ size_t o = off; off += (bytes + 255) & ~(size_t)255; return o; };
    size_t o_counts = alloc(N_NODES*4);
    size_t o_cursor = alloc(N_NODES*4);
    size_t o_offs   = alloc((N_NODES+1)*4);
    size_t o_as     = alloc(N_NODES*HEADS*4);
    size_t o_ad     = alloc(N_NODES*HEADS*4);
    size_t o_invs   = alloc(N_NODES*HEADS*4);
    size_t o_dinv   = alloc(N_NODES*4);
    size_t o_srcs   = alloc(E_TOT*4);
    size_t o_esrt   = alloc((size_t)E_TOT*HEADS*4);
    size_t o_xh     = alloc((size_t)MPAD*KP_GAT*2);
    size_t o_xt     = alloc((size_t)MPAD*NP_GAT*2);
    size_t o_h1     = alloc((size_t)N_NODES*KP_GCN*2);
    size_t o_agg    = alloc((size_t)MPAD*KP_GCN*2);
    size_t o_h2     = alloc((size_t)MPAD*KP_G1*2);
    size_t o_h3     = alloc((size_t)MPAD*KP_G2*2);
    size_t o_h4     = alloc((size_t)MPAD*F_G2*2);
    size_t o_wgatT  = alloc((size_t)NP_GAT*KP_GAT*2);
    size_t o_wgcnT  = alloc((size_t)NP_GCN*KP_GCN*2);
    size_t o_wg1T   = alloc((size_t)NP_G1*KP_G1*2);
    size_t o_wg2T   = alloc((size_t)NP_G2*KP_G2*2);

    int*    counts  = (int*)(ws + o_counts);
    int*    cursor  = (int*)(ws + o_cursor);
    int*    offsets = (int*)(ws + o_offs);
    float*  a_s     = (float*)(ws + o_as);
    float*  a_d     = (float*)(ws + o_ad);
    float*  inv_s   = (float*)(ws + o_invs);
    float*  dinv    = (float*)(ws + o_dinv);
    int*    src_srt = (int*)(ws + o_srcs);
    float*  e_srt   = (float*)(ws + o_esrt);
    half_t* xh      = (half_t*)(ws + o_xh);
    half_t* xt_h    = (half_t*)(ws + o_xt);
    half_t* h1h     = (half_t*)(ws + o_h1);
    half_t* aggh    = (half_t*)(ws + o_agg);
    half_t* h2h     = (half_t*)(ws + o_h2);
    half_t* h3h     = (half_t*)(ws + o_h3);
    half_t* h4h     = (half_t*)(ws + o_h4);
    half_t* WgatT   = (half_t*)(ws + o_wgatT);
    half_t* WgcnT   = (half_t*)(ws + o_wgcnT);
    half_t* Wg1T    = (half_t*)(ws + o_wg1T);
    half_t* Wg2T    = (half_t*)(ws + o_wg2T);

    /* CSR build */
    hipMemsetAsync(counts, 0, N_NODES*4, stream);
    hipMemsetAsync(cursor, 0, N_NODES*4, stream);
    k_count<<<(E_TOT+255)/256, 256, 0, stream>>>(ei, counts);
    k_scan<<<1, 256, 0, stream>>>(counts, offsets);
    k_fill<<<(E_TOT+255)/256, 256, 0, stream>>>(ei, offsets, cursor, src_srt);
    k_dinv<<<(N_NODES+255)/256, 256, 0, stream>>>(offsets, dinv);

    /* fp16 packing */
    k_xh<<<(MPAD*KP_GAT+255)/256, 256, 0, stream>>>(x, xh);
    k_wt<<<(NP_GAT*KP_GAT+255)/256, 256, 0, stream>>>(W_gat, WgatT, F_INPUT, F_GAT, KP_GAT, NP_GAT);
    k_wt<<<(NP_GCN*KP_GCN+255)/256, 256, 0, stream>>>(W_gcn, WgcnT, F_GAT, F_GCN, KP_GCN, NP_GCN);
    k_wt<<<(NP_G1*KP_G1+255)/256, 256, 0, stream>>>(W_g1, Wg1T, F_GCN, F_G1, KP_G1, NP_G1);
    k_wt<<<(NP_G2*KP_G2+255)/256, 256, 0, stream>>>(W_g2, Wg2T, F_G1, F_G2, KP_G2, NP_G2);

    /* GAT: xt = x @ W_gat */
    k_hgemm<<<dim3(NP_GAT/128, MPAD/128), 256, 0, stream>>>(
        xh, WgatT, xt_h, nullptr, F_GAT, NP_GAT, KP_GAT, 1.0f);
    k_attn_ad<<<(N_NODES*HEADS+255)/256, 256, 0, stream>>>(xt_h, att_src, att_dst, a_s, a_d);
    k_softmax<<<(N_NODES*HEADS+255)/256, 256, 0, stream>>>(offsets, src_srt, a_s, a_d, e_srt, inv_s);
    k_gat_agg<<<N_NODES, 192, 0, stream>>>(offsets, src_srt, e_srt, inv_s, xt_h, b_gat, h1h);

    /* GCN aggregate-first: agg = D^-1/2 A D^-1/2 h1, then GEMM w/ fused bias+leaky */
    k_gcn_pre<<<N_NODES, 192, 0, stream>>>(offsets, src_srt, dinv, h1h, aggh);
    k_hgemm<<<dim3(NP_GCN/128, MPAD/128), 256, 0, stream>>>(
        aggh, WgcnT, h2h, b_gcn, F_GCN, KP_G1, KP_GCN, 0.01f);

    /* dense tail */
    k_hgemm<<<dim3(NP_G1/128, MPAD/128), 256, 0, stream>>>(
        h2h, Wg1T, h3h, b_g1, F_G1, KP_G2, KP_G1, 0.01f);
    k_hgemm<<<dim3(NP_G2/128, MPAD/128), 256, 0, stream>>>(
        h3h, Wg2T, h4h, b_g2, F_G2, F_G2, KP_G2, 0.01f);
    k_tail<<<N_NODES/8, 256, 0, stream>>>(h4h, W_fc1, b_fc1, W_fc2, b_fc2,
                                          W_out, b_out, out);
}

// Round 7
// 367.327 us; speedup vs baseline: 3.8371x; 1.0363x over previous
//
#include <hip/hip_runtime.h>
#include <hip/hip_bf16.h>
#include <math.h>

#define N_NODES 10000
#define MPAD    10112    /* 79*128 */
#define N_EDGESI 120000
#define E_TOT   130000   /* with self loops */
#define F_INPUT 66
#define HEADS   10
#define F_HEAD  66
#define F_GAT   660      /* HEADS*F_HEAD */
#define F_GCN   1320
#define F_G1    1000
#define F_G2    64

typedef _Float16 half_t;
typedef __attribute__((ext_vector_type(2))) _Float16 f16x2;
typedef __attribute__((ext_vector_type(4))) _Float16 f16x4;
typedef __attribute__((ext_vector_type(8))) _Float16 f16x8;
typedef __attribute__((ext_vector_type(4))) float f32x4;

/* padded K / N for fp16 MFMA GEMMs (K mult of 64, N mult of 64) */
#define KP_GAT 128
#define NP_GAT 768
#define KP_GCN 704      /* = GAT output padded; also K of GCN GEMM */
#define NP_GCN 1408
#define KP_G1  1344
#define NP_G1  1024
#define KP_G2  1024
#define NP_G2  64

__device__ __forceinline__ float lky(float x, float s){ return x >= 0.f ? x : s*x; }

#if defined(__has_builtin)
#if __has_builtin(__builtin_amdgcn_global_load_lds)
#define HAVE_GLL 1
#endif
#endif

#ifdef HAVE_GLL
#define LDSLOAD16(g, l) __builtin_amdgcn_global_load_lds( \
    (const __attribute__((address_space(1))) void*)(g),   \
    (__attribute__((address_space(3))) void*)(l), 16, 0, 0)
#else
#define LDSLOAD16(g, l) (*(f16x8*)(l) = *(const f16x8*)(g))
#endif

/* ---------------- CSR build ---------------- */

__global__ void k_count(const int* __restrict__ ei, int* __restrict__ counts){
    int e = blockIdx.x*256 + threadIdx.x;
    if (e >= E_TOT) return;
    int dst = (e < N_EDGESI) ? ei[N_EDGESI + e] : (e - N_EDGESI);
    atomicAdd(&counts[dst], 1);
}

__global__ void k_scan(const int* __restrict__ counts, int* __restrict__ offsets){
    __shared__ int sh[256];
    int carry = 0;
    for (int base = 0; base < N_NODES; base += 256){
        int i = base + threadIdx.x;
        int v = (i < N_NODES) ? counts[i] : 0;
        sh[threadIdx.x] = v;
        __syncthreads();
        for (int off = 1; off < 256; off <<= 1){
            int t = (threadIdx.x >= off) ? sh[threadIdx.x - off] : 0;
            __syncthreads();
            sh[threadIdx.x] += t;
            __syncthreads();
        }
        if (i < N_NODES) offsets[i] = carry + sh[threadIdx.x] - v;
        int tot = sh[255];
        __syncthreads();
        carry += tot;
    }
    if (threadIdx.x == 0) offsets[N_NODES] = carry;
}

__global__ void k_fill(const int* __restrict__ ei, const int* __restrict__ offsets,
                       int* __restrict__ cursor, int* __restrict__ src_sorted){
    int e = blockIdx.x*256 + threadIdx.x;
    if (e >= E_TOT) return;
    int s, d;
    if (e < N_EDGESI){ s = ei[e]; d = ei[N_EDGESI + e]; }
    else { s = e - N_EDGESI; d = s; }
    int pos = offsets[d] + atomicAdd(&cursor[d], 1);
    src_sorted[pos] = s;
}

/* ---------------- fp32 -> fp16 packers ---------------- */

__global__ void k_xh(const float* __restrict__ x, half_t* __restrict__ xh){
    int idx = blockIdx.x*256 + threadIdx.x;
    if (idx >= MPAD*KP_GAT) return;
    int r = idx >> 7, c = idx & 127;
    float v = (r < N_NODES && c < F_INPUT) ? x[r*F_INPUT + c] : 0.f;
    xh[idx] = (half_t)v;
}

__global__ void k_wt(const float* __restrict__ W, half_t* __restrict__ WT,
                     int K, int N, int Kp, int Np){
    int idx = blockIdx.x*256 + threadIdx.x;
    if (idx >= Np*Kp) return;
    int n = idx / Kp, k = idx - n*Kp;
    float v = (n < N && k < K) ? W[(size_t)k*N + n] : 0.f;
    WT[idx] = (half_t)v;
}

/* ---------------- fp16 MFMA GEMM (128x64 tile, BK=64, XOR swizzle, XCD remap)
   BM=128/BN=64 doubles the grid vs 128x128: g1 632->1264 blocks (2.5->4.9/CU)
   to fix the measured occupancy limit (18%, MfmaUtil 22%). */
__global__ __launch_bounds__(256)
void k_hgemm(const half_t* __restrict__ A, const half_t* __restrict__ Bt,
             half_t* __restrict__ C, const float* __restrict__ bias,
             int Nreal, int ldc, int Kp, float slope){
    __shared__ half_t As[128*64];
    __shared__ half_t Bs[64*64];
    const int tid = threadIdx.x;
    const int l = tid & 63;
    const int wid = tid >> 6;
    const int wr = wid >> 1, wc = wid & 1;   /* wave covers 64 rows x 32 cols */

    /* XCD-aware bijective remap (m204) */
    const int gx = gridDim.x;
    const int nwg = gx * gridDim.y;
    const int orig = blockIdx.y * gx + blockIdx.x;
    const int q = nwg >> 3, r8 = nwg & 7;
    const int xcd = orig & 7, lin = orig >> 3;
    const int wgid = (xcd < r8 ? xcd*(q+1) : r8*(q+1) + (xcd-r8)*q) + lin;
    const int bx = wgid % gx, by = wgid / gx;

    const int brow = by * 128;
    const int bcol = bx * 64;

    f32x4 acc[4][2] = {};

    for (int k0 = 0; k0 < Kp; k0 += 64){
        #pragma unroll
        for (int i = 0; i < 4; i++){
            int s = tid + i*256;          /* A: 1024 slots */
            int row = s >> 3, chp = s & 7;
            int ch = chp ^ (row & 7);
            LDSLOAD16(A + (size_t)(brow+row)*Kp + k0 + ch*8, &As[s*8]);
        }
        #pragma unroll
        for (int i = 0; i < 2; i++){
            int s = tid + i*256;          /* B: 512 slots */
            int row = s >> 3, chp = s & 7;
            int ch = chp ^ (row & 7);
            LDSLOAD16(Bt + (size_t)(bcol+row)*Kp + k0 + ch*8, &Bs[s*8]);
        }
        __syncthreads();
        #pragma unroll
        for (int t = 0; t < 2; t++){
            f16x8 af[4], bf[2];
            #pragma unroll
            for (int m = 0; m < 4; m++){
                int row = wr*64 + m*16 + (l & 15);
                int ch = (t*4 + (l >> 4)) ^ (row & 7);
                af[m] = *(const f16x8*)&As[row*64 + ch*8];
            }
            #pragma unroll
            for (int n = 0; n < 2; n++){
                int row = wc*32 + n*16 + (l & 15);
                int ch = (t*4 + (l >> 4)) ^ (row & 7);
                bf[n] = *(const f16x8*)&Bs[row*64 + ch*8];
            }
            #pragma unroll
            for (int m = 0; m < 4; m++)
                #pragma unroll
                for (int n = 0; n < 2; n++)
                    acc[m][n] = __builtin_amdgcn_mfma_f32_16x16x32_f16(
                        af[m], bf[n], acc[m][n], 0, 0, 0);
        }
        __syncthreads();
    }

    #pragma unroll
    for (int m = 0; m < 4; m++){
        #pragma unroll
        for (int n = 0; n < 2; n++){
            int col = bcol + wc*32 + n*16 + (l & 15);
            if (col >= ldc) continue;
            float bv = (bias && col < Nreal) ? bias[col] : 0.f;
            #pragma unroll
            for (int r = 0; r < 4; r++){
                int rowg = brow + wr*64 + m*16 + ((l >> 4) << 2) + r;
                float v = (col < Nreal) ? acc[m][n][r] + bv : 0.f;
                v = (v >= 0.f) ? v : slope*v;
                C[(size_t)rowg*ldc + col] = (half_t)v;
            }
        }
    }
}

/* ---------------- GAT attention ---------------- */

__global__ void k_attn_ad(const half_t* __restrict__ xt,
                          const float* __restrict__ att_src, const float* __restrict__ att_dst,
                          float* __restrict__ a_s, float* __restrict__ a_d){
    int t = blockIdx.x*256 + threadIdx.x;
    if (t >= N_NODES*HEADS) return;
    int n = t / HEADS, h = t - (t/HEADS)*HEADS;
    const half_t* xr = xt + (size_t)n*NP_GAT + h*F_HEAD;
    const float* as = att_src + h*F_HEAD;
    const float* ad = att_dst + h*F_HEAD;
    float s = 0.f, d = 0.f;
    #pragma unroll
    for (int f = 0; f < F_HEAD; f += 2){
        f16x2 v = *(const f16x2*)(xr + f);
        float vx = (float)v.x, vy = (float)v.y;
        s += vx*as[f] + vy*as[f+1];
        d += vx*ad[f] + vy*ad[f+1];
    }
    a_s[t] = s; a_d[t] = d;
}

/* fused edge-score + segment softmax: one thread per (node, head) */
__global__ void k_softmax(const int* __restrict__ offsets, const int* __restrict__ src_sorted,
                          const float* __restrict__ a_s, const float* __restrict__ a_d,
                          float* __restrict__ e_sorted, float* __restrict__ inv_s){
    int t = blockIdx.x*256 + threadIdx.x;
    if (t >= N_NODES*HEADS) return;
    int n = t / HEADS, h = t - (t/HEADS)*HEADS;
    int b = offsets[n], e = offsets[n+1];
    float ad_n = a_d[t];
    float m = -INFINITY;
    for (int s = b; s < e; s++){
        float v = lky(a_s[src_sorted[s]*HEADS + h] + ad_n, 0.2f);
        e_sorted[(size_t)s*HEADS + h] = v;
        m = fmaxf(m, v);
    }
    float sum = 0.f;
    for (int s = b; s < e; s++){
        float ex = __expf(e_sorted[(size_t)s*HEADS + h] - m);
        e_sorted[(size_t)s*HEADS + h] = ex;
        sum += ex;
    }
    inv_s[t] = 1.0f / fmaxf(sum, 1e-16f);
}

/* GAT aggregation: block(192) per node, f16x4 per thread, edge loop unrolled x4 */
__global__ __launch_bounds__(192)
void k_gat_agg(const int* __restrict__ offsets, const int* __restrict__ src_sorted,
               const float* __restrict__ e_sorted, const float* __restrict__ inv_s,
               const half_t* __restrict__ xt, const float* __restrict__ b_gat,
               half_t* __restrict__ out){
    int n = blockIdx.x, t = threadIdx.x;
    int f0 = 4*t;
    int h0 = min(f0/F_HEAD, HEADS-1);
    int h1 = min((f0+1)/F_HEAD, HEADS-1);
    int h2 = min((f0+2)/F_HEAD, HEADS-1);
    int h3 = min((f0+3)/F_HEAD, HEADS-1);
    int b = offsets[n], e = offsets[n+1];
    float a0=0.f, a1=0.f, a2=0.f, a3=0.f;
    int s = b;
    for (; s + 4 <= e; s += 4){
        int s0 = src_sorted[s],   s1 = src_sorted[s+1];
        int s2 = src_sorted[s+2], s3 = src_sorted[s+3];
        f16x4 v0 = *(const f16x4*)(xt + (size_t)s0*NP_GAT + f0);
        f16x4 v1 = *(const f16x4*)(xt + (size_t)s1*NP_GAT + f0);
        f16x4 v2 = *(const f16x4*)(xt + (size_t)s2*NP_GAT + f0);
        f16x4 v3 = *(const f16x4*)(xt + (size_t)s3*NP_GAT + f0);
        const float* e0 = e_sorted + (size_t)s*HEADS;
        const float* e1 = e0 + HEADS;
        const float* e2 = e0 + 2*HEADS;
        const float* e3 = e0 + 3*HEADS;
        a0 += e0[h0]*(float)v0.x + e1[h0]*(float)v1.x + e2[h0]*(float)v2.x + e3[h0]*(float)v3.x;
        a1 += e0[h1]*(float)v0.y + e1[h1]*(float)v1.y + e2[h1]*(float)v2.y + e3[h1]*(float)v3.y;
        a2 += e0[h2]*(float)v0.z + e1[h2]*(float)v1.z + e2[h2]*(float)v2.z + e3[h2]*(float)v3.z;
        a3 += e0[h3]*(float)v0.w + e1[h3]*(float)v1.w + e2[h3]*(float)v2.w + e3[h3]*(float)v3.w;
    }
    for (; s < e; s++){
        int s0 = src_sorted[s];
        f16x4 v0 = *(const f16x4*)(xt + (size_t)s0*NP_GAT + f0);
        const float* e0 = e_sorted + (size_t)s*HEADS;
        a0 += e0[h0]*(float)v0.x;
        a1 += e0[h1]*(float)v0.y;
        a2 += e0[h2]*(float)v0.z;
        a3 += e0[h3]*(float)v0.w;
    }
    if (f0 >= KP_GCN) return;        /* t >= 176 */
    half_t* orow = out + (size_t)n*KP_GCN + f0;
    if (f0 < F_GAT){                 /* 660 % 4 == 0: no straddle */
        const float* iv = inv_s + n*HEADS;
        f16x4 r;
        r.x = (half_t)lky(a0*iv[h0] + b_gat[f0  ], 0.01f);
        r.y = (half_t)lky(a1*iv[h1] + b_gat[f0+1], 0.01f);
        r.z = (half_t)lky(a2*iv[h2] + b_gat[f0+2], 0.01f);
        r.w = (half_t)lky(a3*iv[h3] + b_gat[f0+3], 0.01f);
        *(f16x4*)orow = r;
    } else {
        f16x4 z = {(half_t)0.f,(half_t)0.f,(half_t)0.f,(half_t)0.f};
        *(f16x4*)orow = z;
    }
}

/* ---------------- GCN (aggregate-first) ---------------- */

__global__ void k_dinv(const int* __restrict__ offsets, float* __restrict__ dinv){
    int n = blockIdx.x*256 + threadIdx.x;
    if (n >= N_NODES) return;
    float deg = (float)(offsets[n+1] - offsets[n]);
    dinv[n] = rsqrtf(fmaxf(deg, 1.0f));
}

/* agg[n] = dinv[n] * sum_{s in N(n)} dinv[src] * h1[src], edge loop unrolled x4 */
__global__ __launch_bounds__(192)
void k_gcn_pre(const int* __restrict__ offsets, const int* __restrict__ src_sorted,
               const float* __restrict__ dinv, const half_t* __restrict__ h1,
               half_t* __restrict__ agg){
    int n = blockIdx.x, t = threadIdx.x;
    if (t >= 176) return;            /* 176*4 = 704 */
    int f0 = 4*t;
    int b = offsets[n], e = offsets[n+1];
    float a0=0.f, a1=0.f, a2=0.f, a3=0.f;
    int s = b;
    for (; s + 4 <= e; s += 4){
        int s0 = src_sorted[s],   s1 = src_sorted[s+1];
        int s2 = src_sorted[s+2], s3 = src_sorted[s+3];
        float n0 = dinv[s0], n1 = dinv[s1], n2 = dinv[s2], n3 = dinv[s3];
        f16x4 v0 = *(const f16x4*)(h1 + (size_t)s0*KP_GCN + f0);
        f16x4 v1 = *(const f16x4*)(h1 + (size_t)s1*KP_GCN + f0);
        f16x4 v2 = *(const f16x4*)(h1 + (size_t)s2*KP_GCN + f0);
        f16x4 v3 = *(const f16x4*)(h1 + (size_t)s3*KP_GCN + f0);
        a0 += n0*(float)v0.x + n1*(float)v1.x + n2*(float)v2.x + n3*(float)v3.x;
        a1 += n0*(float)v0.y + n1*(float)v1.y + n2*(float)v2.y + n3*(float)v3.y;
        a2 += n0*(float)v0.z + n1*(float)v1.z + n2*(float)v2.z + n3*(float)v3.z;
        a3 += n0*(float)v0.w + n1*(float)v1.w + n2*(float)v2.w + n3*(float)v3.w;
    }
    for (; s < e; s++){
        int s0 = src_sorted[s];
        float n0 = dinv[s0];
        f16x4 v0 = *(const f16x4*)(h1 + (size_t)s0*KP_GCN + f0);
        a0 += n0*(float)v0.x;
        a1 += n0*(float)v0.y;
        a2 += n0*(float)v0.z;
        a3 += n0*(float)v0.w;
    }
    float dn = dinv[n];
    f16x4 r;
    r.x = (half_t)(dn*a0); r.y = (half_t)(dn*a1);
    r.z = (half_t)(dn*a2); r.w = (half_t)(dn*a3);
    *(f16x4*)(agg + (size_t)n*KP_GCN + f0) = r;
}

/* ---------------- fused tail MLP: 64->32->16->1 ---------------- */
__global__ __launch_bounds__(256)
void k_tail(const half_t* __restrict__ h4,
            const float* __restrict__ Wfc1, const float* __restrict__ bfc1,
            const float* __restrict__ Wfc2, const float* __restrict__ bfc2,
            const float* __restrict__ Wout, const float* __restrict__ bout,
            float* __restrict__ out){
    __shared__ float W1[64*32];
    __shared__ float W2[32*16];
    __shared__ float Wo[16];
    __shared__ float b1[32];
    __shared__ float b2[16];
    __shared__ float r1[8][32];
    __shared__ float r2[8][16];
    int tid = threadIdx.x;
    for (int i = tid; i < 64*32; i += 256) W1[i] = Wfc1[i];
    for (int i = tid; i < 32*16; i += 256) W2[i] = Wfc2[i];
    if (tid < 16) Wo[tid] = Wout[tid];
    if (tid < 32) b1[tid] = bfc1[tid];
    if (tid < 16) b2[tid] = bfc2[tid];
    __syncthreads();
    int g = tid >> 5, j = tid & 31;
    int node = blockIdx.x*8 + g;
    const half_t* hr = h4 + (size_t)node*F_G2;
    float acc = 0.f;
    #pragma unroll 8
    for (int i = 0; i < 64; i++) acc += (float)hr[i]*W1[i*32 + j];
    r1[g][j] = lky(acc + b1[j], 0.01f);
    __syncthreads();
    if (j < 16){
        float a2 = 0.f;
        #pragma unroll
        for (int i = 0; i < 32; i++) a2 += r1[g][i]*W2[i*16 + j];
        r2[g][j] = lky(a2 + b2[j], 0.01f);
    }
    __syncthreads();
    if (j == 0){
        float a3 = 0.f;
        #pragma unroll
        for (int i = 0; i < 16; i++) a3 += r2[g][i]*Wo[i];
        out[node] = a3 + bout[0];
    }
}

/* ---------------- launch ---------------- */

extern "C" void kernel_launch(void* const* d_in, const int* in_sizes, int n_in,
                              void* d_out, int out_size, void* d_ws, size_t ws_size,
                              hipStream_t stream){
    const float* x       = (const float*)d_in[0];
    const int*   ei      = (const int*)  d_in[1];
    const float* W_gat   = (const float*)d_in[2];
    const float* att_src = (const float*)d_in[3];
    const float* att_dst = (const float*)d_in[4];
    const float* b_gat   = (const float*)d_in[5];
    const float* W_gcn   = (const float*)d_in[6];
    const float* b_gcn   = (const float*)d_in[7];
    const float* W_g1    = (const float*)d_in[8];
    const float* b_g1    = (const float*)d_in[9];
    const float* W_g2    = (const float*)d_in[10];
    const float* b_g2    = (const float*)d_in[11];
    const float* W_fc1   = (const float*)d_in[12];
    const float* b_fc1   = (const float*)d_in[13];
    const float* W_fc2   = (const float*)d_in[14];
    const float* b_fc2   = (const float*)d_in[15];
    const float* W_out   = (const float*)d_in[16];
    const float* b_out   = (const float*)d_in[17];
    float* out = (float*)d_out;
    char* ws = (char*)d_ws;

    size_t off = 0;
    auto alloc = [&](size_t bytes){ size_t o = off; off += (bytes + 255) & ~(size_t)255; return o; };
    size_t o_counts = alloc(N_NODES*4);
    size_t o_cursor = alloc(N_NODES*4);
    size_t o_offs   = alloc((N_NODES+1)*4);
    size_t o_as     = alloc(N_NODES*HEADS*4);
    size_t o_ad     = alloc(N_NODES*HEADS*4);
    size_t o_invs   = alloc(N_NODES*HEADS*4);
    size_t o_dinv   = alloc(N_NODES*4);
    size_t o_srcs   = alloc(E_TOT*4);
    size_t o_esrt   = alloc((size_t)E_TOT*HEADS*4);
    size_t o_xh     = alloc((size_t)MPAD*KP_GAT*2);
    size_t o_xt     = alloc((size_t)MPAD*NP_GAT*2);
    size_t o_h1     = alloc((size_t)N_NODES*KP_GCN*2);
    size_t o_agg    = alloc((size_t)MPAD*KP_GCN*2);
    size_t o_h2     = alloc((size_t)MPAD*KP_G1*2);
    size_t o_h3     = alloc((size_t)MPAD*KP_G2*2);
    size_t o_h4     = alloc((size_t)MPAD*F_G2*2);
    size_t o_wgatT  = alloc((size_t)NP_GAT*KP_GAT*2);
    size_t o_wgcnT  = alloc((size_t)NP_GCN*KP_GCN*2);
    size_t o_wg1T   = alloc((size_t)NP_G1*KP_G1*2);
    size_t o_wg2T   = alloc((size_t)NP_G2*KP_G2*2);

    int*    counts  = (int*)(ws + o_counts);
    int*    cursor  = (int*)(ws + o_cursor);
    int*    offsets = (int*)(ws + o_offs);
    float*  a_s     = (float*)(ws + o_as);
    float*  a_d     = (float*)(ws + o_ad);
    float*  inv_s   = (float*)(ws + o_invs);
    float*  dinv    = (float*)(ws + o_dinv);
    int*    src_srt = (int*)(ws + o_srcs);
    float*  e_srt   = (float*)(ws + o_esrt);
    half_t* xh      = (half_t*)(ws + o_xh);
    half_t* xt_h    = (half_t*)(ws + o_xt);
    half_t* h1h     = (half_t*)(ws + o_h1);
    half_t* aggh    = (half_t*)(ws + o_agg);
    half_t* h2h     = (half_t*)(ws + o_h2);
    half_t* h3h     = (half_t*)(ws + o_h3);
    half_t* h4h     = (half_t*)(ws + o_h4);
    half_t* WgatT   = (half_t*)(ws + o_wgatT);
    half_t* WgcnT   = (half_t*)(ws + o_wgcnT);
    half_t* Wg1T    = (half_t*)(ws + o_wg1T);
    half_t* Wg2T    = (half_t*)(ws + o_wg2T);

    /* CSR build */
    hipMemsetAsync(counts, 0, N_NODES*4, stream);
    hipMemsetAsync(cursor, 0, N_NODES*4, stream);
    k_count<<<(E_TOT+255)/256, 256, 0, stream>>>(ei, counts);
    k_scan<<<1, 256, 0, stream>>>(counts, offsets);
    k_fill<<<(E_TOT+255)/256, 256, 0, stream>>>(ei, offsets, cursor, src_srt);
    k_dinv<<<(N_NODES+255)/256, 256, 0, stream>>>(offsets, dinv);

    /* fp16 packing */
    k_xh<<<(MPAD*KP_GAT+255)/256, 256, 0, stream>>>(x, xh);
    k_wt<<<(NP_GAT*KP_GAT+255)/256, 256, 0, stream>>>(W_gat, WgatT, F_INPUT, F_GAT, KP_GAT, NP_GAT);
    k_wt<<<(NP_GCN*KP_GCN+255)/256, 256, 0, stream>>>(W_gcn, WgcnT, F_GAT, F_GCN, KP_GCN, NP_GCN);
    k_wt<<<(NP_G1*KP_G1+255)/256, 256, 0, stream>>>(W_g1, Wg1T, F_GCN, F_G1, KP_G1, NP_G1);
    k_wt<<<(NP_G2*KP_G2+255)/256, 256, 0, stream>>>(W_g2, Wg2T, F_G1, F_G2, KP_G2, NP_G2);

    /* GAT: xt = x @ W_gat */
    k_hgemm<<<dim3(NP_GAT/64, MPAD/128), 256, 0, stream>>>(
        xh, WgatT, xt_h, nullptr, F_GAT, NP_GAT, KP_GAT, 1.0f);
    k_attn_ad<<<(N_NODES*HEADS+255)/256, 256, 0, stream>>>(xt_h, att_src, att_dst, a_s, a_d);
    k_softmax<<<(N_NODES*HEADS+255)/256, 256, 0, stream>>>(offsets, src_srt, a_s, a_d, e_srt, inv_s);
    k_gat_agg<<<N_NODES, 192, 0, stream>>>(offsets, src_srt, e_srt, inv_s, xt_h, b_gat, h1h);

    /* GCN aggregate-first: agg = D^-1/2 A D^-1/2 h1, then GEMM w/ fused bias+leaky */
    k_gcn_pre<<<N_NODES, 192, 0, stream>>>(offsets, src_srt, dinv, h1h, aggh);
    k_hgemm<<<dim3(NP_GCN/64, MPAD/128), 256, 0, stream>>>(
        aggh, WgcnT, h2h, b_gcn, F_GCN, KP_G1, KP_GCN, 0.01f);

    /* dense tail */
    k_hgemm<<<dim3(NP_G1/64, MPAD/128), 256, 0, stream>>>(
        h2h, Wg1T, h3h, b_g1, F_G1, KP_G2, KP_G1, 0.01f);
    k_hgemm<<<dim3(NP_G2/64, MPAD/128), 256, 0, stream>>>(
        h3h, Wg2T, h4h, b_g2, F_G2, F_G2, KP_G2, 0.01f);
    k_tail<<<N_NODES/8, 256, 0, stream>>>(h4h, W_fc1, b_fc1, W_fc2, b_fc2,
                                          W_out, b_out, out);
}

// Round 9
// 332.804 us; speedup vs baseline: 4.2351x; 1.1037x over previous
//
#include <hip/hip_runtime.h>
#include <hip/hip_bf16.h>
#include <math.h>

#define N_NODES 10000
#define MPAD    10112    /* 79*128 */
#define N_EDGESI 120000
#define E_TOT   130000   /* with self loops */
#define F_INPUT 66
#define HEADS   10
#define F_HEAD  66
#define F_GAT   660      /* HEADS*F_HEAD */
#define F_GCN   1320
#define F_G1    1000
#define F_G2    64

typedef _Float16 half_t;
typedef __attribute__((ext_vector_type(2))) _Float16 f16x2;
typedef __attribute__((ext_vector_type(4))) _Float16 f16x4;
typedef __attribute__((ext_vector_type(8))) _Float16 f16x8;
typedef __attribute__((ext_vector_type(4))) float f32x4;

/* padded K / N for fp16 MFMA GEMMs (K mult of 64, N mult of 64) */
#define KP_GAT 128
#define NP_GAT 768
#define KP_GCN 704      /* = GAT output padded; also K of GCN GEMM */
#define NP_GCN 1408
#define KP_G1  1344
#define NP_G1  1024
#define KP_G2  1024
#define NP_G2  64

__device__ __forceinline__ float lky(float x, float s){ return x >= 0.f ? x : s*x; }

#if defined(__has_builtin)
#if __has_builtin(__builtin_amdgcn_global_load_lds)
#define HAVE_GLL 1
#endif
#endif

#ifdef HAVE_GLL
#define LDSLOAD16(g, l) __builtin_amdgcn_global_load_lds( \
    (const __attribute__((address_space(1))) void*)(g),   \
    (__attribute__((address_space(3))) void*)(l), 16, 0, 0)
#else
#define LDSLOAD16(g, l) (*(f16x8*)(l) = *(const f16x8*)(g))
#endif

/* ---------------- CSR build ---------------- */

__global__ void k_count(const int* __restrict__ ei, int* __restrict__ counts){
    int e = blockIdx.x*256 + threadIdx.x;
    if (e >= E_TOT) return;
    int dst = (e < N_EDGESI) ? ei[N_EDGESI + e] : (e - N_EDGESI);
    atomicAdd(&counts[dst], 1);
}

/* single-block scan, wave-shuffle based: 10 chunks x 3 barriers (vs 640
   barriers in the 256-thread LDS-tree version -> ~20x less serial time). */
__global__ __launch_bounds__(1024)
void k_scan(const int* __restrict__ counts, int* __restrict__ offsets){
    __shared__ int wsum[16];            /* 1024/64 waves */
    const int lane = threadIdx.x & 63;
    const int wave = threadIdx.x >> 6;
    int carry = 0;
    for (int base = 0; base < N_NODES; base += 1024){
        int i = base + threadIdx.x;
        int v = (i < N_NODES) ? counts[i] : 0;
        /* inclusive scan within wave (no barriers) */
        int x = v;
        #pragma unroll
        for (int off = 1; off < 64; off <<= 1){
            int y = __shfl_up(x, off, 64);
            if (lane >= off) x += y;
        }
        if (lane == 63) wsum[wave] = x;
        __syncthreads();
        /* wave 0 scans the 16 wave totals */
        if (wave == 0){
            int w = (lane < 16) ? wsum[lane] : 0;
            #pragma unroll
            for (int off = 1; off < 16; off <<= 1){
                int y = __shfl_up(w, off, 64);
                if (lane >= off) w += y;
            }
            if (lane < 16) wsum[lane] = w;   /* inclusive scan of wave sums */
        }
        __syncthreads();
        int prefix = (wave > 0) ? wsum[wave-1] : 0;
        if (i < N_NODES) offsets[i] = carry + prefix + x - v;  /* exclusive */
        carry += wsum[15];
        __syncthreads();                     /* wsum reused next chunk */
    }
    if (threadIdx.x == 0) offsets[N_NODES] = carry;
}

__global__ void k_fill(const int* __restrict__ ei, const int* __restrict__ offsets,
                       int* __restrict__ cursor, int* __restrict__ src_sorted){
    int e = blockIdx.x*256 + threadIdx.x;
    if (e >= E_TOT) return;
    int s, d;
    if (e < N_EDGESI){ s = ei[e]; d = ei[N_EDGESI + e]; }
    else { s = e - N_EDGESI; d = s; }
    int pos = offsets[d] + atomicAdd(&cursor[d], 1);
    src_sorted[pos] = s;
}

/* ---------------- fp32 -> fp16 packers ---------------- */

__global__ void k_xh(const float* __restrict__ x, half_t* __restrict__ xh){
    int idx = blockIdx.x*256 + threadIdx.x;
    if (idx >= MPAD*KP_GAT) return;
    int r = idx >> 7, c = idx & 127;
    float v = (r < N_NODES && c < F_INPUT) ? x[r*F_INPUT + c] : 0.f;
    xh[idx] = (half_t)v;
}

__global__ void k_wt(const float* __restrict__ W, half_t* __restrict__ WT,
                     int K, int N, int Kp, int Np){
    int idx = blockIdx.x*256 + threadIdx.x;
    if (idx >= Np*Kp) return;
    int n = idx / Kp, k = idx - n*Kp;
    float v = (n < N && k < K) ? W[(size_t)k*N + n] : 0.f;
    WT[idx] = (half_t)v;
}

/* ---------------- fp16 MFMA GEMM (128x64 tile, BK=64, XOR swizzle, XCD remap) */
__global__ __launch_bounds__(256)
void k_hgemm(const half_t* __restrict__ A, const half_t* __restrict__ Bt,
             half_t* __restrict__ C, const float* __restrict__ bias,
             int Nreal, int ldc, int Kp, float slope){
    __shared__ half_t As[128*64];
    __shared__ half_t Bs[64*64];
    const int tid = threadIdx.x;
    const int l = tid & 63;
    const int wid = tid >> 6;
    const int wr = wid >> 1, wc = wid & 1;   /* wave covers 64 rows x 32 cols */

    /* XCD-aware bijective remap (m204) */
    const int gx = gridDim.x;
    const int nwg = gx * gridDim.y;
    const int orig = blockIdx.y * gx + blockIdx.x;
    const int q = nwg >> 3, r8 = nwg & 7;
    const int xcd = orig & 7, lin = orig >> 3;
    const int wgid = (xcd < r8 ? xcd*(q+1) : r8*(q+1) + (xcd-r8)*q) + lin;
    const int bx = wgid % gx, by = wgid / gx;

    const int brow = by * 128;
    const int bcol = bx * 64;

    f32x4 acc[4][2] = {};

    for (int k0 = 0; k0 < Kp; k0 += 64){
        #pragma unroll
        for (int i = 0; i < 4; i++){
            int s = tid + i*256;          /* A: 1024 slots */
            int row = s >> 3, chp = s & 7;
            int ch = chp ^ (row & 7);
            LDSLOAD16(A + (size_t)(brow+row)*Kp + k0 + ch*8, &As[s*8]);
        }
        #pragma unroll
        for (int i = 0; i < 2; i++){
            int s = tid + i*256;          /* B: 512 slots */
            int row = s >> 3, chp = s & 7;
            int ch = chp ^ (row & 7);
            LDSLOAD16(Bt + (size_t)(bcol+row)*Kp + k0 + ch*8, &Bs[s*8]);
        }
        __syncthreads();
        #pragma unroll
        for (int t = 0; t < 2; t++){
            f16x8 af[4], bf[2];
            #pragma unroll
            for (int m = 0; m < 4; m++){
                int row = wr*64 + m*16 + (l & 15);
                int ch = (t*4 + (l >> 4)) ^ (row & 7);
                af[m] = *(const f16x8*)&As[row*64 + ch*8];
            }
            #pragma unroll
            for (int n = 0; n < 2; n++){
                int row = wc*32 + n*16 + (l & 15);
                int ch = (t*4 + (l >> 4)) ^ (row & 7);
                bf[n] = *(const f16x8*)&Bs[row*64 + ch*8];
            }
            #pragma unroll
            for (int m = 0; m < 4; m++)
                #pragma unroll
                for (int n = 0; n < 2; n++)
                    acc[m][n] = __builtin_amdgcn_mfma_f32_16x16x32_f16(
                        af[m], bf[n], acc[m][n], 0, 0, 0);
        }
        __syncthreads();
    }

    #pragma unroll
    for (int m = 0; m < 4; m++){
        #pragma unroll
        for (int n = 0; n < 2; n++){
            int col = bcol + wc*32 + n*16 + (l & 15);
            if (col >= ldc) continue;
            float bv = (bias && col < Nreal) ? bias[col] : 0.f;
            #pragma unroll
            for (int r = 0; r < 4; r++){
                int rowg = brow + wr*64 + m*16 + ((l >> 4) << 2) + r;
                float v = (col < Nreal) ? acc[m][n][r] + bv : 0.f;
                v = (v >= 0.f) ? v : slope*v;
                C[(size_t)rowg*ldc + col] = (half_t)v;
            }
        }
    }
}

/* ---------------- GAT attention ---------------- */

__global__ void k_attn_ad(const half_t* __restrict__ xt,
                          const float* __restrict__ att_src, const float* __restrict__ att_dst,
                          float* __restrict__ a_s, float* __restrict__ a_d){
    int t = blockIdx.x*256 + threadIdx.x;
    if (t >= N_NODES*HEADS) return;
    int n = t / HEADS, h = t - (t/HEADS)*HEADS;
    const half_t* xr = xt + (size_t)n*NP_GAT + h*F_HEAD;
    const float* as = att_src + h*F_HEAD;
    const float* ad = att_dst + h*F_HEAD;
    float s = 0.f, d = 0.f;
    #pragma unroll
    for (int f = 0; f < F_HEAD; f += 2){
        f16x2 v = *(const f16x2*)(xr + f);
        float vx = (float)v.x, vy = (float)v.y;
        s += vx*as[f] + vy*as[f+1];
        d += vx*ad[f] + vy*ad[f+1];
    }
    a_s[t] = s; a_d[t] = d;
}

/* fused edge-score + segment softmax: one thread per (node, head) */
__global__ void k_softmax(const int* __restrict__ offsets, const int* __restrict__ src_sorted,
                          const float* __restrict__ a_s, const float* __restrict__ a_d,
                          float* __restrict__ e_sorted, float* __restrict__ inv_s){
    int t = blockIdx.x*256 + threadIdx.x;
    if (t >= N_NODES*HEADS) return;
    int n = t / HEADS, h = t - (t/HEADS)*HEADS;
    int b = offsets[n], e = offsets[n+1];
    float ad_n = a_d[t];
    float m = -INFINITY;
    for (int s = b; s < e; s++){
        float v = lky(a_s[src_sorted[s]*HEADS + h] + ad_n, 0.2f);
        e_sorted[(size_t)s*HEADS + h] = v;
        m = fmaxf(m, v);
    }
    float sum = 0.f;
    for (int s = b; s < e; s++){
        float ex = __expf(e_sorted[(size_t)s*HEADS + h] - m);
        e_sorted[(size_t)s*HEADS + h] = ex;
        sum += ex;
    }
    inv_s[t] = 1.0f / fmaxf(sum, 1e-16f);
}

/* GAT aggregation: block(192) per node, f16x4 per thread, edge loop unrolled x4 */
__global__ __launch_bounds__(192)
void k_gat_agg(const int* __restrict__ offsets, const int* __restrict__ src_sorted,
               const float* __restrict__ e_sorted, const float* __restrict__ inv_s,
               const half_t* __restrict__ xt, const float* __restrict__ b_gat,
               half_t* __restrict__ out){
    int n = blockIdx.x, t = threadIdx.x;
    int f0 = 4*t;
    int h0 = min(f0/F_HEAD, HEADS-1);
    int h1 = min((f0+1)/F_HEAD, HEADS-1);
    int h2 = min((f0+2)/F_HEAD, HEADS-1);
    int h3 = min((f0+3)/F_HEAD, HEADS-1);
    int b = offsets[n], e = offsets[n+1];
    float a0=0.f, a1=0.f, a2=0.f, a3=0.f;
    int s = b;
    for (; s + 4 <= e; s += 4){
        int s0 = src_sorted[s],   s1 = src_sorted[s+1];
        int s2 = src_sorted[s+2], s3 = src_sorted[s+3];
        f16x4 v0 = *(const f16x4*)(xt + (size_t)s0*NP_GAT + f0);
        f16x4 v1 = *(const f16x4*)(xt + (size_t)s1*NP_GAT + f0);
        f16x4 v2 = *(const f16x4*)(xt + (size_t)s2*NP_GAT + f0);
        f16x4 v3 = *(const f16x4*)(xt + (size_t)s3*NP_GAT + f0);
        const float* e0 = e_sorted + (size_t)s*HEADS;
        const float* e1 = e0 + HEADS;
        const float* e2 = e0 + 2*HEADS;
        const float* e3 = e0 + 3*HEADS;
        a0 += e0[h0]*(float)v0.x + e1[h0]*(float)v1.x + e2[h0]*(float)v2.x + e3[h0]*(float)v3.x;
        a1 += e0[h1]*(float)v0.y + e1[h1]*(float)v1.y + e2[h1]*(float)v2.y + e3[h1]*(float)v3.y;
        a2 += e0[h2]*(float)v0.z + e1[h2]*(float)v1.z + e2[h2]*(float)v2.z + e3[h2]*(float)v3.z;
        a3 += e0[h3]*(float)v0.w + e1[h3]*(float)v1.w + e2[h3]*(float)v2.w + e3[h3]*(float)v3.w;
    }
    for (; s < e; s++){
        int s0 = src_sorted[s];
        f16x4 v0 = *(const f16x4*)(xt + (size_t)s0*NP_GAT + f0);
        const float* e0 = e_sorted + (size_t)s*HEADS;
        a0 += e0[h0]*(float)v0.x;
        a1 += e0[h1]*(float)v0.y;
        a2 += e0[h2]*(float)v0.z;
        a3 += e0[h3]*(float)v0.w;
    }
    if (f0 >= KP_GCN) return;        /* t >= 176 */
    half_t* orow = out + (size_t)n*KP_GCN + f0;
    if (f0 < F_GAT){                 /* 660 % 4 == 0: no straddle */
        const float* iv = inv_s + n*HEADS;
        f16x4 r;
        r.x = (half_t)lky(a0*iv[h0] + b_gat[f0  ], 0.01f);
        r.y = (half_t)lky(a1*iv[h1] + b_gat[f0+1], 0.01f);
        r.z = (half_t)lky(a2*iv[h2] + b_gat[f0+2], 0.01f);
        r.w = (half_t)lky(a3*iv[h3] + b_gat[f0+3], 0.01f);
        *(f16x4*)orow = r;
    } else {
        f16x4 z = {(half_t)0.f,(half_t)0.f,(half_t)0.f,(half_t)0.f};
        *(f16x4*)orow = z;
    }
}

/* ---------------- GCN (aggregate-first) ---------------- */

__global__ void k_dinv(const int* __restrict__ offsets, float* __restrict__ dinv){
    int n = blockIdx.x*256 + threadIdx.x;
    if (n >= N_NODES) return;
    float deg = (float)(offsets[n+1] - offsets[n]);
    dinv[n] = rsqrtf(fmaxf(deg, 1.0f));
}

/* agg[n] = dinv[n] * sum_{s in N(n)} dinv[src] * h1[src], edge loop unrolled x4 */
__global__ __launch_bounds__(192)
void k_gcn_pre(const int* __restrict__ offsets, const int* __restrict__ src_sorted,
               const float* __restrict__ dinv, const half_t* __restrict__ h1,
               half_t* __restrict__ agg){
    int n = blockIdx.x, t = threadIdx.x;
    if (t >= 176) return;            /* 176*4 = 704 */
    int f0 = 4*t;
    int b = offsets[n], e = offsets[n+1];
    float a0=0.f, a1=0.f, a2=0.f, a3=0.f;
    int s = b;
    for (; s + 4 <= e; s += 4){
        int s0 = src_sorted[s],   s1 = src_sorted[s+1];
        int s2 = src_sorted[s+2], s3 = src_sorted[s+3];
        float n0 = dinv[s0], n1 = dinv[s1], n2 = dinv[s2], n3 = dinv[s3];
        f16x4 v0 = *(const f16x4*)(h1 + (size_t)s0*KP_GCN + f0);
        f16x4 v1 = *(const f16x4*)(h1 + (size_t)s1*KP_GCN + f0);
        f16x4 v2 = *(const f16x4*)(h1 + (size_t)s2*KP_GCN + f0);
        f16x4 v3 = *(const f16x4*)(h1 + (size_t)s3*KP_GCN + f0);
        a0 += n0*(float)v0.x + n1*(float)v1.x + n2*(float)v2.x + n3*(float)v3.x;
        a1 += n0*(float)v0.y + n1*(float)v1.y + n2*(float)v2.y + n3*(float)v3.y;
        a2 += n0*(float)v0.z + n1*(float)v1.z + n2*(float)v2.z + n3*(float)v3.z;
        a3 += n0*(float)v0.w + n1*(float)v1.w + n2*(float)v2.w + n3*(float)v3.w;
    }
    for (; s < e; s++){
        int s0 = src_sorted[s];
        float n0 = dinv[s0];
        f16x4 v0 = *(const f16x4*)(h1 + (size_t)s0*KP_GCN + f0);
        a0 += n0*(float)v0.x;
        a1 += n0*(float)v0.y;
        a2 += n0*(float)v0.z;
        a3 += n0*(float)v0.w;
    }
    float dn = dinv[n];
    f16x4 r;
    r.x = (half_t)(dn*a0); r.y = (half_t)(dn*a1);
    r.z = (half_t)(dn*a2); r.w = (half_t)(dn*a3);
    *(f16x4*)(agg + (size_t)n*KP_GCN + f0) = r;
}

/* ---------------- fused tail MLP: 64->32->16->1 ---------------- */
__global__ __launch_bounds__(256)
void k_tail(const half_t* __restrict__ h4,
            const float* __restrict__ Wfc1, const float* __restrict__ bfc1,
            const float* __restrict__ Wfc2, const float* __restrict__ bfc2,
            const float* __restrict__ Wout, const float* __restrict__ bout,
            float* __restrict__ out){
    __shared__ float W1[64*32];
    __shared__ float W2[32*16];
    __shared__ float Wo[16];
    __shared__ float b1[32];
    __shared__ float b2[16];
    __shared__ float r1[8][32];
    __shared__ float r2[8][16];
    int tid = threadIdx.x;
    for (int i = tid; i < 64*32; i += 256) W1[i] = Wfc1[i];
    for (int i = tid; i < 32*16; i += 256) W2[i] = Wfc2[i];
    if (tid < 16) Wo[tid] = Wout[tid];
    if (tid < 32) b1[tid] = bfc1[tid];
    if (tid < 16) b2[tid] = bfc2[tid];
    __syncthreads();
    int g = tid >> 5, j = tid & 31;
    int node = blockIdx.x*8 + g;
    const half_t* hr = h4 + (size_t)node*F_G2;
    float acc = 0.f;
    #pragma unroll 8
    for (int i = 0; i < 64; i++) acc += (float)hr[i]*W1[i*32 + j];
    r1[g][j] = lky(acc + b1[j], 0.01f);
    __syncthreads();
    if (j < 16){
        float a2 = 0.f;
        #pragma unroll
        for (int i = 0; i < 32; i++) a2 += r1[g][i]*W2[i*16 + j];
        r2[g][j] = lky(a2 + b2[j], 0.01f);
    }
    __syncthreads();
    if (j == 0){
        float a3 = 0.f;
        #pragma unroll
        for (int i = 0; i < 16; i++) a3 += r2[g][i]*Wo[i];
        out[node] = a3 + bout[0];
    }
}

/* ---------------- launch ---------------- */

extern "C" void kernel_launch(void* const* d_in, const int* in_sizes, int n_in,
                              void* d_out, int out_size, void* d_ws, size_t ws_size,
                              hipStream_t stream){
    const float* x       = (const float*)d_in[0];
    const int*   ei      = (const int*)  d_in[1];
    const float* W_gat   = (const float*)d_in[2];
    const float* att_src = (const float*)d_in[3];
    const float* att_dst = (const float*)d_in[4];
    const float* b_gat   = (const float*)d_in[5];
    const float* W_gcn   = (const float*)d_in[6];
    const float* b_gcn   = (const float*)d_in[7];
    const float* W_g1    = (const float*)d_in[8];
    const float* b_g1    = (const float*)d_in[9];
    const float* W_g2    = (const float*)d_in[10];
    const float* b_g2    = (const float*)d_in[11];
    const float* W_fc1   = (const float*)d_in[12];
    const float* b_fc1   = (const float*)d_in[13];
    const float* W_fc2   = (const float*)d_in[14];
    const float* b_fc2   = (const float*)d_in[15];
    const float* W_out   = (const float*)d_in[16];
    const float* b_out   = (const float*)d_in[17];
    float* out = (float*)d_out;
    char* ws = (char*)d_ws;

    size_t off = 0;
    auto alloc = [&](size_t bytes){ size_t o = off; off += (bytes + 255) & ~(size_t)255; return o; };
    size_t o_counts = alloc(N_NODES*4);
    size_t o_cursor = alloc(N_NODES*4);
    size_t o_offs   = alloc((N_NODES+1)*4);
    size_t o_as     = alloc(N_NODES*HEADS*4);
    size_t o_ad     = alloc(N_NODES*HEADS*4);
    size_t o_invs   = alloc(N_NODES*HEADS*4);
    size_t o_dinv   = alloc(N_NODES*4);
    size_t o_srcs   = alloc(E_TOT*4);
    size_t o_esrt   = alloc((size_t)E_TOT*HEADS*4);
    size_t o_xh     = alloc((size_t)MPAD*KP_GAT*2);
    size_t o_xt     = alloc((size_t)MPAD*NP_GAT*2);
    size_t o_h1     = alloc((size_t)N_NODES*KP_GCN*2);
    size_t o_agg    = alloc((size_t)MPAD*KP_GCN*2);
    size_t o_h2     = alloc((size_t)MPAD*KP_G1*2);
    size_t o_h3     = alloc((size_t)MPAD*KP_G2*2);
    size_t o_h4     = alloc((size_t)MPAD*F_G2*2);
    size_t o_wgatT  = alloc((size_t)NP_GAT*KP_GAT*2);
    size_t o_wgcnT  = alloc((size_t)NP_GCN*KP_GCN*2);
    size_t o_wg1T   = alloc((size_t)NP_G1*KP_G1*2);
    size_t o_wg2T   = alloc((size_t)NP_G2*KP_G2*2);

    int*    counts  = (int*)(ws + o_counts);
    int*    cursor  = (int*)(ws + o_cursor);
    int*    offsets = (int*)(ws + o_offs);
    float*  a_s     = (float*)(ws + o_as);
    float*  a_d     = (float*)(ws + o_ad);
    float*  inv_s   = (float*)(ws + o_invs);
    float*  dinv    = (float*)(ws + o_dinv);
    int*    src_srt = (int*)(ws + o_srcs);
    float*  e_srt   = (float*)(ws + o_esrt);
    half_t* xh      = (half_t*)(ws + o_xh);
    half_t* xt_h    = (half_t*)(ws + o_xt);
    half_t* h1h     = (half_t*)(ws + o_h1);
    half_t* aggh    = (half_t*)(ws + o_agg);
    half_t* h2h     = (half_t*)(ws + o_h2);
    half_t* h3h     = (half_t*)(ws + o_h3);
    half_t* h4h     = (half_t*)(ws + o_h4);
    half_t* WgatT   = (half_t*)(ws + o_wgatT);
    half_t* WgcnT   = (half_t*)(ws + o_wgcnT);
    half_t* Wg1T    = (half_t*)(ws + o_wg1T);
    half_t* Wg2T    = (half_t*)(ws + o_wg2T);

    /* CSR build */
    hipMemsetAsync(counts, 0, N_NODES*4, stream);
    hipMemsetAsync(cursor, 0, N_NODES*4, stream);
    k_count<<<(E_TOT+255)/256, 256, 0, stream>>>(ei, counts);
    k_scan<<<1, 1024, 0, stream>>>(counts, offsets);
    k_fill<<<(E_TOT+255)/256, 256, 0, stream>>>(ei, offsets, cursor, src_srt);
    k_dinv<<<(N_NODES+255)/256, 256, 0, stream>>>(offsets, dinv);

    /* fp16 packing */
    k_xh<<<(MPAD*KP_GAT+255)/256, 256, 0, stream>>>(x, xh);
    k_wt<<<(NP_GAT*KP_GAT+255)/256, 256, 0, stream>>>(W_gat, WgatT, F_INPUT, F_GAT, KP_GAT, NP_GAT);
    k_wt<<<(NP_GCN*KP_GCN+255)/256, 256, 0, stream>>>(W_gcn, WgcnT, F_GAT, F_GCN, KP_GCN, NP_GCN);
    k_wt<<<(NP_G1*KP_G1+255)/256, 256, 0, stream>>>(W_g1, Wg1T, F_GCN, F_G1, KP_G1, NP_G1);
    k_wt<<<(NP_G2*KP_G2+255)/256, 256, 0, stream>>>(W_g2, Wg2T, F_G1, F_G2, KP_G2, NP_G2);

    /* GAT: xt = x @ W_gat */
    k_hgemm<<<dim3(NP_GAT/64, MPAD/128), 256, 0, stream>>>(
        xh, WgatT, xt_h, nullptr, F_GAT, NP_GAT, KP_GAT, 1.0f);
    k_attn_ad<<<(N_NODES*HEADS+255)/256, 256, 0, stream>>>(xt_h, att_src, att_dst, a_s, a_d);
    k_softmax<<<(N_NODES*HEADS+255)/256, 256, 0, stream>>>(offsets, src_srt, a_s, a_d, e_srt, inv_s);
    k_gat_agg<<<N_NODES, 192, 0, stream>>>(offsets, src_srt, e_srt, inv_s, xt_h, b_gat, h1h);

    /* GCN aggregate-first: agg = D^-1/2 A D^-1/2 h1, then GEMM w/ fused bias+leaky */
    k_gcn_pre<<<N_NODES, 192, 0, stream>>>(offsets, src_srt, dinv, h1h, aggh);
    k_hgemm<<<dim3(NP_GCN/64, MPAD/128), 256, 0, stream>>>(
        aggh, WgcnT, h2h, b_gcn, F_GCN, KP_G1, KP_GCN, 0.01f);

    /* dense tail */
    k_hgemm<<<dim3(NP_G1/64, MPAD/128), 256, 0, stream>>>(
        h2h, Wg1T, h3h, b_g1, F_G1, KP_G2, KP_G1, 0.01f);
    k_hgemm<<<dim3(NP_G2/64, MPAD/128), 256, 0, stream>>>(
        h3h, Wg2T, h4h, b_g2, F_G2, F_G2, KP_G2, 0.01f);
    k_tail<<<N_NODES/8, 256, 0, stream>>>(h4h, W_fc1, b_fc1, W_fc2, b_fc2,
                                          W_out, b_out, out);
}

// Round 10
// 331.287 us; speedup vs baseline: 4.2545x; 1.0046x over previous
//
#include <hip/hip_runtime.h>
#include <hip/hip_bf16.h>
#include <math.h>

#define N_NODES 10000
#define MPAD    10112    /* 79*128 */
#define N_EDGESI 120000
#define E_TOT   130000   /* with self loops */
#define F_INPUT 66
#define HEADS   10
#define F_HEAD  66
#define F_GAT   660      /* HEADS*F_HEAD */
#define F_GCN   1320
#define F_G1    1000
#define F_G2    64

typedef _Float16 half_t;
typedef __attribute__((ext_vector_type(2))) _Float16 f16x2;
typedef __attribute__((ext_vector_type(4))) _Float16 f16x4;
typedef __attribute__((ext_vector_type(8))) _Float16 f16x8;
typedef __attribute__((ext_vector_type(4))) float f32x4;

/* padded K / N for fp16 MFMA GEMMs (K mult of 64, N mult of 64) */
#define KP_GAT 128
#define NP_GAT 768
#define KP_GCN 704      /* = GAT output padded; also K of GCN GEMM */
#define NP_GCN 1408
#define KP_G1  1344
#define NP_G1  1024
#define KP_G2  1024
#define NP_G2  64

__device__ __forceinline__ float lky(float x, float s){ return x >= 0.f ? x : s*x; }

#if defined(__has_builtin)
#if __has_builtin(__builtin_amdgcn_global_load_lds)
#define HAVE_GLL 1
#endif
#endif

#ifdef HAVE_GLL
#define LDSLOAD16(g, l) __builtin_amdgcn_global_load_lds( \
    (const __attribute__((address_space(1))) void*)(g),   \
    (__attribute__((address_space(3))) void*)(l), 16, 0, 0)
#else
#define LDSLOAD16(g, l) (*(f16x8*)(l) = *(const f16x8*)(g))
#endif

/* ---------------- CSR build ---------------- */

__global__ void k_count(const int* __restrict__ ei, int* __restrict__ counts){
    int e = blockIdx.x*256 + threadIdx.x;
    if (e >= E_TOT) return;
    int dst = (e < N_EDGESI) ? ei[N_EDGESI + e] : (e - N_EDGESI);
    atomicAdd(&counts[dst], 1);
}

/* single-block scan, wave-shuffle based (proven r9); dinv fused:
   deg == counts[i], so dinv needs no extra kernel. */
__global__ __launch_bounds__(1024)
void k_scan(const int* __restrict__ counts, int* __restrict__ offsets,
            float* __restrict__ dinv){
    __shared__ int wsum[16];            /* 1024/64 waves */
    const int lane = threadIdx.x & 63;
    const int wave = threadIdx.x >> 6;
    int carry = 0;
    for (int base = 0; base < N_NODES; base += 1024){
        int i = base + threadIdx.x;
        int v = (i < N_NODES) ? counts[i] : 0;
        if (i < N_NODES) dinv[i] = rsqrtf(fmaxf((float)v, 1.0f));
        /* inclusive scan within wave (no barriers) */
        int x = v;
        #pragma unroll
        for (int off = 1; off < 64; off <<= 1){
            int y = __shfl_up(x, off, 64);
            if (lane >= off) x += y;
        }
        if (lane == 63) wsum[wave] = x;
        __syncthreads();
        /* wave 0 scans the 16 wave totals */
        if (wave == 0){
            int w = (lane < 16) ? wsum[lane] : 0;
            #pragma unroll
            for (int off = 1; off < 16; off <<= 1){
                int y = __shfl_up(w, off, 64);
                if (lane >= off) w += y;
            }
            if (lane < 16) wsum[lane] = w;   /* inclusive scan of wave sums */
        }
        __syncthreads();
        int prefix = (wave > 0) ? wsum[wave-1] : 0;
        if (i < N_NODES) offsets[i] = carry + prefix + x - v;  /* exclusive */
        carry += wsum[15];
        __syncthreads();                     /* wsum reused next chunk */
    }
    if (threadIdx.x == 0) offsets[N_NODES] = carry;
}

__global__ void k_fill(const int* __restrict__ ei, const int* __restrict__ offsets,
                       int* __restrict__ cursor, int* __restrict__ src_sorted){
    int e = blockIdx.x*256 + threadIdx.x;
    if (e >= E_TOT) return;
    int s, d;
    if (e < N_EDGESI){ s = ei[e]; d = ei[N_EDGESI + e]; }
    else { s = e - N_EDGESI; d = s; }
    int pos = offsets[d] + atomicAdd(&cursor[d], 1);
    src_sorted[pos] = s;
}

/* ---------------- fp32 -> fp16 packers ---------------- */

__global__ void k_xh(const float* __restrict__ x, half_t* __restrict__ xh){
    int idx = blockIdx.x*256 + threadIdx.x;
    if (idx >= MPAD*KP_GAT) return;
    int r = idx >> 7, c = idx & 127;
    float v = (r < N_NODES && c < F_INPUT) ? x[r*F_INPUT + c] : 0.f;
    xh[idx] = (half_t)v;
}

__global__ void k_wt(const float* __restrict__ W, half_t* __restrict__ WT,
                     int K, int N, int Kp, int Np){
    int idx = blockIdx.x*256 + threadIdx.x;
    if (idx >= Np*Kp) return;
    int n = idx / Kp, k = idx - n*Kp;
    float v = (n < N && k < K) ? W[(size_t)k*N + n] : 0.f;
    WT[idx] = (half_t)v;
}

/* ---------------- fp16 MFMA GEMM (128x64 tile, BK=64, XOR swizzle, XCD remap) */
__global__ __launch_bounds__(256)
void k_hgemm(const half_t* __restrict__ A, const half_t* __restrict__ Bt,
             half_t* __restrict__ C, const float* __restrict__ bias,
             int Nreal, int ldc, int Kp, float slope){
    __shared__ half_t As[128*64];
    __shared__ half_t Bs[64*64];
    const int tid = threadIdx.x;
    const int l = tid & 63;
    const int wid = tid >> 6;
    const int wr = wid >> 1, wc = wid & 1;   /* wave covers 64 rows x 32 cols */

    /* XCD-aware bijective remap (m204) */
    const int gx = gridDim.x;
    const int nwg = gx * gridDim.y;
    const int orig = blockIdx.y * gx + blockIdx.x;
    const int q = nwg >> 3, r8 = nwg & 7;
    const int xcd = orig & 7, lin = orig >> 3;
    const int wgid = (xcd < r8 ? xcd*(q+1) : r8*(q+1) + (xcd-r8)*q) + lin;
    const int bx = wgid % gx, by = wgid / gx;

    const int brow = by * 128;
    const int bcol = bx * 64;

    f32x4 acc[4][2] = {};

    for (int k0 = 0; k0 < Kp; k0 += 64){
        #pragma unroll
        for (int i = 0; i < 4; i++){
            int s = tid + i*256;          /* A: 1024 slots */
            int row = s >> 3, chp = s & 7;
            int ch = chp ^ (row & 7);
            LDSLOAD16(A + (size_t)(brow+row)*Kp + k0 + ch*8, &As[s*8]);
        }
        #pragma unroll
        for (int i = 0; i < 2; i++){
            int s = tid + i*256;          /* B: 512 slots */
            int row = s >> 3, chp = s & 7;
            int ch = chp ^ (row & 7);
            LDSLOAD16(Bt + (size_t)(bcol+row)*Kp + k0 + ch*8, &Bs[s*8]);
        }
        __syncthreads();
        #pragma unroll
        for (int t = 0; t < 2; t++){
            f16x8 af[4], bf[2];
            #pragma unroll
            for (int m = 0; m < 4; m++){
                int row = wr*64 + m*16 + (l & 15);
                int ch = (t*4 + (l >> 4)) ^ (row & 7);
                af[m] = *(const f16x8*)&As[row*64 + ch*8];
            }
            #pragma unroll
            for (int n = 0; n < 2; n++){
                int row = wc*32 + n*16 + (l & 15);
                int ch = (t*4 + (l >> 4)) ^ (row & 7);
                bf[n] = *(const f16x8*)&Bs[row*64 + ch*8];
            }
            #pragma unroll
            for (int m = 0; m < 4; m++)
                #pragma unroll
                for (int n = 0; n < 2; n++)
                    acc[m][n] = __builtin_amdgcn_mfma_f32_16x16x32_f16(
                        af[m], bf[n], acc[m][n], 0, 0, 0);
        }
        __syncthreads();
    }

    #pragma unroll
    for (int m = 0; m < 4; m++){
        #pragma unroll
        for (int n = 0; n < 2; n++){
            int col = bcol + wc*32 + n*16 + (l & 15);
            if (col >= ldc) continue;
            float bv = (bias && col < Nreal) ? bias[col] : 0.f;
            #pragma unroll
            for (int r = 0; r < 4; r++){
                int rowg = brow + wr*64 + m*16 + ((l >> 4) << 2) + r;
                float v = (col < Nreal) ? acc[m][n][r] + bv : 0.f;
                v = (v >= 0.f) ? v : slope*v;
                C[(size_t)rowg*ldc + col] = (half_t)v;
            }
        }
    }
}

/* ---------------- GAT attention ---------------- */

__global__ void k_attn_ad(const half_t* __restrict__ xt,
                          const float* __restrict__ att_src, const float* __restrict__ att_dst,
                          float* __restrict__ a_s, float* __restrict__ a_d){
    int t = blockIdx.x*256 + threadIdx.x;
    if (t >= N_NODES*HEADS) return;
    int n = t / HEADS, h = t - (t/HEADS)*HEADS;
    const half_t* xr = xt + (size_t)n*NP_GAT + h*F_HEAD;
    const float* as = att_src + h*F_HEAD;
    const float* ad = att_dst + h*F_HEAD;
    float s = 0.f, d = 0.f;
    #pragma unroll
    for (int f = 0; f < F_HEAD; f += 2){
        f16x2 v = *(const f16x2*)(xr + f);
        float vx = (float)v.x, vy = (float)v.y;
        s += vx*as[f] + vy*as[f+1];
        d += vx*ad[f] + vy*ad[f+1];
    }
    a_s[t] = s; a_d[t] = d;
}

/* fused edge-score + segment softmax: one thread per (node, head) */
__global__ void k_softmax(const int* __restrict__ offsets, const int* __restrict__ src_sorted,
                          const float* __restrict__ a_s, const float* __restrict__ a_d,
                          float* __restrict__ e_sorted, float* __restrict__ inv_s){
    int t = blockIdx.x*256 + threadIdx.x;
    if (t >= N_NODES*HEADS) return;
    int n = t / HEADS, h = t - (t/HEADS)*HEADS;
    int b = offsets[n], e = offsets[n+1];
    float ad_n = a_d[t];
    float m = -INFINITY;
    for (int s = b; s < e; s++){
        float v = lky(a_s[src_sorted[s]*HEADS + h] + ad_n, 0.2f);
        e_sorted[(size_t)s*HEADS + h] = v;
        m = fmaxf(m, v);
    }
    float sum = 0.f;
    for (int s = b; s < e; s++){
        float ex = __expf(e_sorted[(size_t)s*HEADS + h] - m);
        e_sorted[(size_t)s*HEADS + h] = ex;
        sum += ex;
    }
    inv_s[t] = 1.0f / fmaxf(sum, 1e-16f);
}

/* GAT aggregation: block(192) per node, f16x4 per thread, edge loop x4.
   Threads <165 cover the 660 REAL columns only (xt cols 660..767 are zeros
   -> reading them was 14% wasted gather traffic); threads 165..175 write
   the h1 pad columns [660,704) directly. */
__global__ __launch_bounds__(192)
void k_gat_agg(const int* __restrict__ offsets, const int* __restrict__ src_sorted,
               const float* __restrict__ e_sorted, const float* __restrict__ inv_s,
               const half_t* __restrict__ xt, const float* __restrict__ b_gat,
               half_t* __restrict__ out){
    int n = blockIdx.x, t = threadIdx.x;
    int f0 = 4*t;
    if (t < 165){
        int h0 = f0/F_HEAD;
        int h1 = (f0+1)/F_HEAD;
        int h2 = (f0+2)/F_HEAD;
        int h3 = (f0+3)/F_HEAD;
        int b = offsets[n], e = offsets[n+1];
        float a0=0.f, a1=0.f, a2=0.f, a3=0.f;
        int s = b;
        for (; s + 4 <= e; s += 4){
            int s0 = src_sorted[s],   s1 = src_sorted[s+1];
            int s2 = src_sorted[s+2], s3 = src_sorted[s+3];
            f16x4 v0 = *(const f16x4*)(xt + (size_t)s0*NP_GAT + f0);
            f16x4 v1 = *(const f16x4*)(xt + (size_t)s1*NP_GAT + f0);
            f16x4 v2 = *(const f16x4*)(xt + (size_t)s2*NP_GAT + f0);
            f16x4 v3 = *(const f16x4*)(xt + (size_t)s3*NP_GAT + f0);
            const float* e0 = e_sorted + (size_t)s*HEADS;
            const float* e1 = e0 + HEADS;
            const float* e2 = e0 + 2*HEADS;
            const float* e3 = e0 + 3*HEADS;
            a0 += e0[h0]*(float)v0.x + e1[h0]*(float)v1.x + e2[h0]*(float)v2.x + e3[h0]*(float)v3.x;
            a1 += e0[h1]*(float)v0.y + e1[h1]*(float)v1.y + e2[h1]*(float)v2.y + e3[h1]*(float)v3.y;
            a2 += e0[h2]*(float)v0.z + e1[h2]*(float)v1.z + e2[h2]*(float)v2.z + e3[h2]*(float)v3.z;
            a3 += e0[h3]*(float)v0.w + e1[h3]*(float)v1.w + e2[h3]*(float)v2.w + e3[h3]*(float)v3.w;
        }
        for (; s < e; s++){
            int s0 = src_sorted[s];
            f16x4 v0 = *(const f16x4*)(xt + (size_t)s0*NP_GAT + f0);
            const float* e0 = e_sorted + (size_t)s*HEADS;
            a0 += e0[h0]*(float)v0.x;
            a1 += e0[h1]*(float)v0.y;
            a2 += e0[h2]*(float)v0.z;
            a3 += e0[h3]*(float)v0.w;
        }
        const float* iv = inv_s + n*HEADS;
        f16x4 r;
        r.x = (half_t)lky(a0*iv[h0] + b_gat[f0  ], 0.01f);
        r.y = (half_t)lky(a1*iv[h1] + b_gat[f0+1], 0.01f);
        r.z = (half_t)lky(a2*iv[h2] + b_gat[f0+2], 0.01f);
        r.w = (half_t)lky(a3*iv[h3] + b_gat[f0+3], 0.01f);
        *(f16x4*)(out + (size_t)n*KP_GCN + f0) = r;
    } else if (t < 176){
        f16x4 z = {(half_t)0.f,(half_t)0.f,(half_t)0.f,(half_t)0.f};
        *(f16x4*)(out + (size_t)n*KP_GCN + f0) = z;
    }
}

/* ---------------- GCN (aggregate-first) ---------------- */

/* agg[n] = dinv[n] * sum dinv[src]*h1[src]; threads <165 gather the 660
   real cols (h1 cols 660..703 are zeros); threads 165..175 write pad. */
__global__ __launch_bounds__(192)
void k_gcn_pre(const int* __restrict__ offsets, const int* __restrict__ src_sorted,
               const float* __restrict__ dinv, const half_t* __restrict__ h1,
               half_t* __restrict__ agg){
    int n = blockIdx.x, t = threadIdx.x;
    int f0 = 4*t;
    if (t < 165){
        int b = offsets[n], e = offsets[n+1];
        float a0=0.f, a1=0.f, a2=0.f, a3=0.f;
        int s = b;
        for (; s + 4 <= e; s += 4){
            int s0 = src_sorted[s],   s1 = src_sorted[s+1];
            int s2 = src_sorted[s+2], s3 = src_sorted[s+3];
            float n0 = dinv[s0], n1 = dinv[s1], n2 = dinv[s2], n3 = dinv[s3];
            f16x4 v0 = *(const f16x4*)(h1 + (size_t)s0*KP_GCN + f0);
            f16x4 v1 = *(const f16x4*)(h1 + (size_t)s1*KP_GCN + f0);
            f16x4 v2 = *(const f16x4*)(h1 + (size_t)s2*KP_GCN + f0);
            f16x4 v3 = *(const f16x4*)(h1 + (size_t)s3*KP_GCN + f0);
            a0 += n0*(float)v0.x + n1*(float)v1.x + n2*(float)v2.x + n3*(float)v3.x;
            a1 += n0*(float)v0.y + n1*(float)v1.y + n2*(float)v2.y + n3*(float)v3.y;
            a2 += n0*(float)v0.z + n1*(float)v1.z + n2*(float)v2.z + n3*(float)v3.z;
            a3 += n0*(float)v0.w + n1*(float)v1.w + n2*(float)v2.w + n3*(float)v3.w;
        }
        for (; s < e; s++){
            int s0 = src_sorted[s];
            float n0 = dinv[s0];
            f16x4 v0 = *(const f16x4*)(h1 + (size_t)s0*KP_GCN + f0);
            a0 += n0*(float)v0.x;
            a1 += n0*(float)v0.y;
            a2 += n0*(float)v0.z;
            a3 += n0*(float)v0.w;
        }
        float dn = dinv[n];
        f16x4 r;
        r.x = (half_t)(dn*a0); r.y = (half_t)(dn*a1);
        r.z = (half_t)(dn*a2); r.w = (half_t)(dn*a3);
        *(f16x4*)(agg + (size_t)n*KP_GCN + f0) = r;
    } else if (t < 176){
        f16x4 z = {(half_t)0.f,(half_t)0.f,(half_t)0.f,(half_t)0.f};
        *(f16x4*)(agg + (size_t)n*KP_GCN + f0) = z;
    }
}

/* ---------------- fused tail MLP: 64->32->16->1 ---------------- */
__global__ __launch_bounds__(256)
void k_tail(const half_t* __restrict__ h4,
            const float* __restrict__ Wfc1, const float* __restrict__ bfc1,
            const float* __restrict__ Wfc2, const float* __restrict__ bfc2,
            const float* __restrict__ Wout, const float* __restrict__ bout,
            float* __restrict__ out){
    __shared__ float W1[64*32];
    __shared__ float W2[32*16];
    __shared__ float Wo[16];
    __shared__ float b1[32];
    __shared__ float b2[16];
    __shared__ float r1[8][32];
    __shared__ float r2[8][16];
    int tid = threadIdx.x;
    for (int i = tid; i < 64*32; i += 256) W1[i] = Wfc1[i];
    for (int i = tid; i < 32*16; i += 256) W2[i] = Wfc2[i];
    if (tid < 16) Wo[tid] = Wout[tid];
    if (tid < 32) b1[tid] = bfc1[tid];
    if (tid < 16) b2[tid] = bfc2[tid];
    __syncthreads();
    int g = tid >> 5, j = tid & 31;
    int node = blockIdx.x*8 + g;
    const half_t* hr = h4 + (size_t)node*F_G2;
    float acc = 0.f;
    #pragma unroll 8
    for (int i = 0; i < 64; i++) acc += (float)hr[i]*W1[i*32 + j];
    r1[g][j] = lky(acc + b1[j], 0.01f);
    __syncthreads();
    if (j < 16){
        float a2 = 0.f;
        #pragma unroll
        for (int i = 0; i < 32; i++) a2 += r1[g][i]*W2[i*16 + j];
        r2[g][j] = lky(a2 + b2[j], 0.01f);
    }
    __syncthreads();
    if (j == 0){
        float a3 = 0.f;
        #pragma unroll
        for (int i = 0; i < 16; i++) a3 += r2[g][i]*Wo[i];
        out[node] = a3 + bout[0];
    }
}

/* ---------------- launch ---------------- */

extern "C" void kernel_launch(void* const* d_in, const int* in_sizes, int n_in,
                              void* d_out, int out_size, void* d_ws, size_t ws_size,
                              hipStream_t stream){
    const float* x       = (const float*)d_in[0];
    const int*   ei      = (const int*)  d_in[1];
    const float* W_gat   = (const float*)d_in[2];
    const float* att_src = (const float*)d_in[3];
    const float* att_dst = (const float*)d_in[4];
    const float* b_gat   = (const float*)d_in[5];
    const float* W_gcn   = (const float*)d_in[6];
    const float* b_gcn   = (const float*)d_in[7];
    const float* W_g1    = (const float*)d_in[8];
    const float* b_g1    = (const float*)d_in[9];
    const float* W_g2    = (const float*)d_in[10];
    const float* b_g2    = (const float*)d_in[11];
    const float* W_fc1   = (const float*)d_in[12];
    const float* b_fc1   = (const float*)d_in[13];
    const float* W_fc2   = (const float*)d_in[14];
    const float* b_fc2   = (const float*)d_in[15];
    const float* W_out   = (const float*)d_in[16];
    const float* b_out   = (const float*)d_in[17];
    float* out = (float*)d_out;
    char* ws = (char*)d_ws;

    size_t off = 0;
    auto alloc = [&](size_t bytes){ size_t o = off; off += (bytes + 255) & ~(size_t)255; return o; };
    size_t o_counts = alloc(N_NODES*4);
    size_t o_cursor = alloc(N_NODES*4);
    size_t o_offs   = alloc((N_NODES+1)*4);
    size_t o_as     = alloc(N_NODES*HEADS*4);
    size_t o_ad     = alloc(N_NODES*HEADS*4);
    size_t o_invs   = alloc(N_NODES*HEADS*4);
    size_t o_dinv   = alloc(N_NODES*4);
    size_t o_srcs   = alloc(E_TOT*4);
    size_t o_esrt   = alloc((size_t)E_TOT*HEADS*4);
    size_t o_xh     = alloc((size_t)MPAD*KP_GAT*2);
    size_t o_xt     = alloc((size_t)MPAD*NP_GAT*2);
    size_t o_h1     = alloc((size_t)N_NODES*KP_GCN*2);
    size_t o_agg    = alloc((size_t)MPAD*KP_GCN*2);
    size_t o_h2     = alloc((size_t)MPAD*KP_G1*2);
    size_t o_h3     = alloc((size_t)MPAD*KP_G2*2);
    size_t o_h4     = alloc((size_t)MPAD*F_G2*2);
    size_t o_wgatT  = alloc((size_t)NP_GAT*KP_GAT*2);
    size_t o_wgcnT  = alloc((size_t)NP_GCN*KP_GCN*2);
    size_t o_wg1T   = alloc((size_t)NP_G1*KP_G1*2);
    size_t o_wg2T   = alloc((size_t)NP_G2*KP_G2*2);

    int*    counts  = (int*)(ws + o_counts);
    int*    cursor  = (int*)(ws + o_cursor);
    int*    offsets = (int*)(ws + o_offs);
    float*  a_s     = (float*)(ws + o_as);
    float*  a_d     = (float*)(ws + o_ad);
    float*  inv_s   = (float*)(ws + o_invs);
    float*  dinv    = (float*)(ws + o_dinv);
    int*    src_srt = (int*)(ws + o_srcs);
    float*  e_srt   = (float*)(ws + o_esrt);
    half_t* xh      = (half_t*)(ws + o_xh);
    half_t* xt_h    = (half_t*)(ws + o_xt);
    half_t* h1h     = (half_t*)(ws + o_h1);
    half_t* aggh    = (half_t*)(ws + o_agg);
    half_t* h2h     = (half_t*)(ws + o_h2);
    half_t* h3h     = (half_t*)(ws + o_h3);
    half_t* h4h     = (half_t*)(ws + o_h4);
    half_t* WgatT   = (half_t*)(ws + o_wgatT);
    half_t* WgcnT   = (half_t*)(ws + o_wgcnT);
    half_t* Wg1T    = (half_t*)(ws + o_wg1T);
    half_t* Wg2T    = (half_t*)(ws + o_wg2T);

    /* CSR build (counts+cursor adjacent, padded: one memset covers both) */
    hipMemsetAsync(ws + o_counts, 0, o_offs - o_counts, stream);
    k_count<<<(E_TOT+255)/256, 256, 0, stream>>>(ei, counts);
    k_scan<<<1, 1024, 0, stream>>>(counts, offsets, dinv);
    k_fill<<<(E_TOT+255)/256, 256, 0, stream>>>(ei, offsets, cursor, src_srt);

    /* fp16 packing */
    k_xh<<<(MPAD*KP_GAT+255)/256, 256, 0, stream>>>(x, xh);
    k_wt<<<(NP_GAT*KP_GAT+255)/256, 256, 0, stream>>>(W_gat, WgatT, F_INPUT, F_GAT, KP_GAT, NP_GAT);
    k_wt<<<(NP_GCN*KP_GCN+255)/256, 256, 0, stream>>>(W_gcn, WgcnT, F_GAT, F_GCN, KP_GCN, NP_GCN);
    k_wt<<<(NP_G1*KP_G1+255)/256, 256, 0, stream>>>(W_g1, Wg1T, F_GCN, F_G1, KP_G1, NP_G1);
    k_wt<<<(NP_G2*KP_G2+255)/256, 256, 0, stream>>>(W_g2, Wg2T, F_G1, F_G2, KP_G2, NP_G2);

    /* GAT: xt = x @ W_gat */
    k_hgemm<<<dim3(NP_GAT/64, MPAD/128), 256, 0, stream>>>(
        xh, WgatT, xt_h, nullptr, F_GAT, NP_GAT, KP_GAT, 1.0f);
    k_attn_ad<<<(N_NODES*HEADS+255)/256, 256, 0, stream>>>(xt_h, att_src, att_dst, a_s, a_d);
    k_softmax<<<(N_NODES*HEADS+255)/256, 256, 0, stream>>>(offsets, src_srt, a_s, a_d, e_srt, inv_s);
    k_gat_agg<<<N_NODES, 192, 0, stream>>>(offsets, src_srt, e_srt, inv_s, xt_h, b_gat, h1h);

    /* GCN aggregate-first: agg = D^-1/2 A D^-1/2 h1, then GEMM w/ fused bias+leaky */
    k_gcn_pre<<<N_NODES, 192, 0, stream>>>(offsets, src_srt, dinv, h1h, aggh);
    k_hgemm<<<dim3(NP_GCN/64, MPAD/128), 256, 0, stream>>>(
        aggh, WgcnT, h2h, b_gcn, F_GCN, KP_G1, KP_GCN, 0.01f);

    /* dense tail */
    k_hgemm<<<dim3(NP_G1/64, MPAD/128), 256, 0, stream>>>(
        h2h, Wg1T, h3h, b_g1, F_G1, KP_G2, KP_G1, 0.01f);
    k_hgemm<<<dim3(NP_G2/64, MPAD/128), 256, 0, stream>>>(
        h3h, Wg2T, h4h, b_g2, F_G2, F_G2, KP_G2, 0.01f);
    k_tail<<<N_NODES/8, 256, 0, stream>>>(h4h, W_fc1, b_fc1, W_fc2, b_fc2,
                                          W_out, b_out, out);
}